// Round 18
// baseline (2520.018 us; speedup 1.0000x reference)
//
#include <hip/hip_runtime.h>
#include <hip/hip_bf16.h>

#define D128 128
#define STAGE 12288

typedef __attribute__((ext_vector_type(8))) short bf16x8;
typedef __attribute__((ext_vector_type(4))) float f32x4;

__device__ inline unsigned short f2bf(float f) {
    unsigned u = __float_as_uint(f);
    u = u + 0x7fffu + ((u >> 16) & 1u);
    return (unsigned short)(u >> 16);
}
__device__ inline float bf2f(unsigned short h) {
    return __uint_as_float(((unsigned)h) << 16);
}
__device__ inline float fast_tanh(float x) {
    float e = __expf(2.f * x);
    return 1.f - 2.f * __builtin_amdgcn_rcpf(e + 1.f);
}

// stage a 128x128 bf16 W into LDS with 16B-slot XOR swizzle (slot ^= row&7)
__device__ __forceinline__ void stage_w(const unsigned short* __restrict__ Wt,
                                        unsigned short* lw, int t)
{
    const uint4* srcW = (const uint4*)Wt;
    uint4* dstW = (uint4*)lw;
    for (int i = t; i < 2048; i += 256) {
        int row = i >> 4, sl = i & 15;
        dstW[row * 16 + (sl ^ (row & 7))] = srcW[i];
    }
}
__device__ __forceinline__ bf16x8 read_w(const unsigned short* lw, int row, int kt, int lq)
{
    int slot = (kt * 4 + lq) ^ (row & 7);
    return *(const bf16x8*)(lw + row * 128 + slot * 8);
}

// wave-parallel exclusive scan of arr[0..n) into ofs[0..n], one 64-lane wave
__device__ __forceinline__ void wave_scan(const int* arr, int* ofs, int n, int lane)
{
    int k = (n + 63) >> 6;
    int base = lane * k;
    int sum = 0;
    for (int i = 0; i < k; i++) { int idx = base + i; if (idx < n) sum += arr[idx]; }
    int pre = sum;
    for (int off = 1; off < 64; off <<= 1) {
        int u = __shfl(pre, (lane - off) & 63);
        if (lane >= off) pre += u;
    }
    int run = pre - sum;
    for (int i = 0; i < k; i++) { int idx = base + i; if (idx < n) { ofs[idx] = run; run += arr[idx]; } }
    if (lane == 63) ofs[n] = run;
}

// ---------------- per-rel pre-scaled bf16 feature conversion ----------------
__global__ __launch_bounds__(256) void xconv_scaled(
    const float* __restrict__ in, const int* __restrict__ degs,
    unsigned* __restrict__ out, int nrows)
{
    int t = threadIdx.x;
    int lane = t & 63, rr = t >> 6;
    int row = blockIdx.x * 4 + rr;
    if (row >= nrows) return;
    float sc = rsqrtf((float)max(degs[row], 1));
    float2 v = ((const float2*)(in + (size_t)row * 128))[lane];
    out[(size_t)row * 64 + lane] =
        (unsigned)f2bf(v.x * sc) | ((unsigned)f2bf(v.y * sc) << 16);
}

// ---------------- weight transpose + convert: Wt[n][k] = W[k][n] ----------------
__global__ void wconv_t(const float* __restrict__ W_blocks, const float* __restrict__ W1,
                        unsigned short* __restrict__ wt)
{
    int m = blockIdx.x;  // 0..15
    const float* src = (m < 15) ? (W_blocks + (size_t)m * 16384) : W1;
    unsigned short* dst = wt + (size_t)m * 16384;
    for (int i = threadIdx.x; i < 16384; i += 256) {
        int n = i >> 7, k = i & 127;
        dst[i] = f2bf(src[k * 128 + n]);
    }
}

// ================= partitioned CSR build (16384 edges/block; 256-wide buckets) ==========
struct BuildArgs {
    const int* esrc[10]; const int* edst[10];
    int* histD; int* histS;
    int cumBlk[11]; int dstColBase[11]; int srcColBase[11]; int E[10];
};

__global__ __launch_bounds__(256) void part_count(BuildArgs A)
{
    __shared__ int hd[320], hs[320];
    int blk = blockIdx.x, t = threadIdx.x;
    int r = 0;
    while (r < 9 && blk >= A.cumBlk[r + 1]) r++;
    int blkInRel = blk - A.cumBlk[r];
    int nbD = A.dstColBase[r + 1] - A.dstColBase[r];
    int nbS = A.srcColBase[r + 1] - A.srcColBase[r];
    for (int i = t; i < nbD; i += 256) hd[i] = 0;
    for (int i = t; i < nbS; i += 256) hs[i] = 0;
    __syncthreads();
    int e0 = blkInRel * 16384;
    const int* sp = A.esrc[r];
    const int* dp = A.edst[r];
    int E = A.E[r];
#pragma unroll 4
    for (int j = 0; j < 64; j++) {
        int e = e0 + j * 256 + t;
        if (e < E) {
            atomicAdd(&hd[dp[e] >> 8], 1);
            atomicAdd(&hs[sp[e] >> 8], 1);
        }
    }
    __syncthreads();
    int cd = A.dstColBase[r], cs = A.srcColBase[r];
    for (int i = t; i < nbD; i += 256)
        A.histD[(size_t)(cd + i) * 80 + blkInRel] = hd[i];
    for (int i = t; i < nbS; i += 256)
        A.histS[(size_t)(cs + i) * 80 + blkInRel] = hs[i];
}

struct ScanArgs { int* hist; int* totals; int colBase[11]; int cumBlk[11]; };

__global__ __launch_bounds__(256) void col_scan(ScanArgs A)
{
    __shared__ int v[80];
    int col = blockIdx.x, t = threadIdx.x;
    int r = 0;
    while (r < 9 && col >= A.colBase[r + 1]) r++;
    int nblk = A.cumBlk[r + 1] - A.cumBlk[r];
    for (int i = t; i < nblk; i += 256) v[i] = A.hist[(size_t)col * 80 + i];
    __syncthreads();
    if (t == 0) {
        int run = 0;
        for (int i = 0; i < nblk; i++) { int c = v[i]; v[i] = run; run += c; }
        A.totals[col] = run;
    }
    __syncthreads();
    for (int i = t; i < nblk; i += 256) A.hist[(size_t)col * 80 + i] = v[i];
}

__global__ __launch_bounds__(256) void base_scan(const int* __restrict__ totals,
                                                 int* __restrict__ colbase, int n)
{
    __shared__ int v[2200];
    int t = threadIdx.x;
    for (int i = t; i < n; i += 256) v[i] = totals[i];
    __syncthreads();
    if (t == 0) {
        int run = 0;
        for (int i = 0; i < n; i++) { int c = v[i]; v[i] = run; run += c; }
        v[n] = run;
    }
    __syncthreads();
    for (int i = t; i <= n; i += 256) colbase[i] = v[i];
}

// fused scatter with chunked LDS staging: bucket-sorted flushes, contiguous cursors
struct ScatArgs {
    const int* esrc[10]; const int* edst[10];
    const int* histD; const int* colbaseD;
    const int* histS; const int* colbaseS;
    int* epart; unsigned char* spart;
    int cumBlk[11]; int dstColBase[11]; int srcColBase[11]; int E[10];
};

__global__ __launch_bounds__(256) void scatter_all(ScatArgs A)
{
    __shared__ int stageE[4096];
    __shared__ unsigned short bidE[4096];
    __shared__ unsigned short bidS[4096];
    __shared__ unsigned char stageS[4096];
    __shared__ int gbaseD[320], gcurD[320], lhistD[320], lofsD[321];
    __shared__ int gbaseS[320], gcurS[320], lhistS[320], lofsS[321];

    int blk = blockIdx.x, t = threadIdx.x;
    int r = 0;
    while (r < 9 && blk >= A.cumBlk[r + 1]) r++;
    int blkInRel = blk - A.cumBlk[r];
    int cd = A.dstColBase[r], cs = A.srcColBase[r];
    int nbD = A.dstColBase[r + 1] - cd;
    int nbS = A.srcColBase[r + 1] - cs;
    for (int i = t; i < nbD; i += 256) {
        gbaseD[i] = A.colbaseD[cd + i] + A.histD[(size_t)(cd + i) * 80 + blkInRel];
        gcurD[i] = 0;
    }
    for (int i = t; i < nbS; i += 256) {
        gbaseS[i] = A.colbaseS[cs + i] + A.histS[(size_t)(cs + i) * 80 + blkInRel];
        gcurS[i] = 0;
    }
    const int* sp = A.esrc[r];
    const int* dp = A.edst[r];
    int E = A.E[r];
    int blkbase = blkInRel * 16384;

    for (int c = 0; c < 4; c++) {
        int e0 = blkbase + c * 4096;
        int sv[16], dv[16];
#pragma unroll
        for (int j = 0; j < 16; j++) {
            int e = e0 + j * 256 + t;
            sv[j] = (e < E) ? sp[e] : -1;
            dv[j] = (e < E) ? dp[e] : 0;
        }
        for (int i = t; i < nbD; i += 256) lhistD[i] = 0;
        for (int i = t; i < nbS; i += 256) lhistS[i] = 0;
        __syncthreads();
#pragma unroll
        for (int j = 0; j < 16; j++) {
            if (sv[j] >= 0) {
                atomicAdd(&lhistD[dv[j] >> 8], 1);
                atomicAdd(&lhistS[sv[j] >> 8], 1);
            }
        }
        __syncthreads();
        if (t < 64) wave_scan(lhistD, lofsD, nbD, t);
        else if (t < 128) wave_scan(lhistS, lofsS, nbS, t - 64);
        __syncthreads();
        for (int i = t; i < nbD; i += 256) lhistD[i] = 0;
        for (int i = t; i < nbS; i += 256) lhistS[i] = 0;
        __syncthreads();
#pragma unroll
        for (int j = 0; j < 16; j++) {
            if (sv[j] >= 0) {
                int bd = dv[j] >> 8;
                int p = atomicAdd(&lhistD[bd], 1);
                int ix = lofsD[bd] + p;
                stageE[ix] = (sv[j] & 0x1FFFF) | ((dv[j] & 255) << 17);
                bidE[ix] = (unsigned short)bd;
                int bs = sv[j] >> 8;
                int q = atomicAdd(&lhistS[bs], 1);
                int iy = lofsS[bs] + q;
                stageS[iy] = (unsigned char)(sv[j] & 255);
                bidS[iy] = (unsigned short)bs;
            }
        }
        __syncthreads();
        int cntv = lofsD[nbD];
        for (int i = t; i < cntv; i += 256) {
            int b = bidE[i];
            A.epart[gbaseD[b] + gcurD[b] + i - lofsD[b]] = stageE[i];
        }
        for (int i = t; i < cntv; i += 256) {
            int b = bidS[i];
            A.spart[(size_t)gbaseS[b] + gcurS[b] + i - lofsS[b]] = stageS[i];
        }
        __syncthreads();
        for (int i = t; i < nbD; i += 256) gcurD[i] += lofsD[i + 1] - lofsD[i];
        for (int i = t; i < nbS; i += 256) gcurS[i] += lofsS[i + 1] - lofsS[i];
        __syncthreads();
    }
}

// per-256-src-bucket degree count
struct DegArgs {
    const unsigned char* spart; const int* colbase;
    int* degs;
    int colBase[11]; int degsBase[10]; int ns[10];
};

__global__ __launch_bounds__(256) void deg_count(DegArgs A)
{
    __shared__ int lc[256];
    int col = blockIdx.x, t = threadIdx.x;
    int r = 0;
    while (r < 9 && col >= A.colBase[r + 1]) r++;
    int b = col - A.colBase[r];
    lc[t] = 0;
    __syncthreads();
    int start = A.colbase[col], end = A.colbase[col + 1];
    for (int i = start + t; i < end; i += 256)
        atomicAdd(&lc[A.spart[i]], 1);
    __syncthreads();
    int s = b * 256 + t;
    if (s < A.ns[r]) A.degs[A.degsBase[r] + s] = lc[t];
}

// ---------------- fused bucket-sort + gather (per 256-dst bucket) ----------------
// counting-sorts the bucket's epart segment in LDS, then accumulates X rows per dst.
__global__ __launch_bounds__(256) void bucket_gather(
    const unsigned* __restrict__ Xb, const int* __restrict__ epart,
    const int* __restrict__ colbase, int colBase0,
    unsigned* __restrict__ aggb, int nd)
{
    __shared__ int stage[STAGE];
    __shared__ int lhist[256], lofs[257];
    int b = blockIdx.x, t = threadIdx.x;
    int col = colBase0 + b;
    int start = colbase[col], end = colbase[col + 1];
    int total = end - start;
    int main_ = min(total, STAGE);

    lhist[t] = 0;
    __syncthreads();
    for (int i = t; i < main_; i += 256)
        atomicAdd(&lhist[(epart[start + i] >> 17) & 255], 1);
    __syncthreads();
    if (t < 64) wave_scan(lhist, lofs, 256, t);
    __syncthreads();
    lhist[t] = 0;
    __syncthreads();
    for (int i = t; i < main_; i += 256) {
        int v = epart[start + i];
        int b8 = (v >> 17) & 255;
        int p = atomicAdd(&lhist[b8], 1);
        stage[lofs[b8] + p] = v & 0x1FFFF;
    }
    __syncthreads();

    int lane = t & 63, sw = t >> 6;
    for (int d8 = sw; d8 < 256; d8 += 4) {
        int d = b * 256 + d8;
        if (d >= nd) continue;
        int sb = lofs[d8], se = lofs[d8 + 1];
        int cnt = se - sb;
        float a0 = 0.f, a1 = 0.f;
        int i = sb;
        for (; i + 4 <= se; i += 4) {
            int s0 = stage[i], s1 = stage[i + 1], s2 = stage[i + 2], s3 = stage[i + 3];
            unsigned x0 = Xb[(size_t)s0 * 64 + lane];
            unsigned x1 = Xb[(size_t)s1 * 64 + lane];
            unsigned x2 = Xb[(size_t)s2 * 64 + lane];
            unsigned x3 = Xb[(size_t)s3 * 64 + lane];
            a0 += bf2f((unsigned short)(x0 & 0xffff)) + bf2f((unsigned short)(x1 & 0xffff))
                + bf2f((unsigned short)(x2 & 0xffff)) + bf2f((unsigned short)(x3 & 0xffff));
            a1 += bf2f((unsigned short)(x0 >> 16)) + bf2f((unsigned short)(x1 >> 16))
                + bf2f((unsigned short)(x2 >> 16)) + bf2f((unsigned short)(x3 >> 16));
        }
        for (; i < se; i++) {
            int s0 = stage[i];
            unsigned x0 = Xb[(size_t)s0 * 64 + lane];
            a0 += bf2f((unsigned short)(x0 & 0xffff));
            a1 += bf2f((unsigned short)(x0 >> 16));
        }
        // astronomically-rare overflow remainder: scan unsorted tail from global
        for (int j = main_; j < total; j++) {
            int v = epart[start + j];
            if (((v >> 17) & 255) == d8) {
                int s0 = v & 0x1FFFF;
                unsigned x0 = Xb[(size_t)s0 * 64 + lane];
                a0 += bf2f((unsigned short)(x0 & 0xffff));
                a1 += bf2f((unsigned short)(x0 >> 16));
                cnt++;
            }
        }
        float sc = rsqrtf((float)max(cnt, 1));
        a0 *= sc; a1 *= sc;
        aggb[(size_t)d * 64 + lane] = (unsigned)f2bf(a0) | ((unsigned)f2bf(a1) << 16);
    }
}

// ---------------- GEMM epilogue: bf16 store + fused BN stats ----------------
__device__ __forceinline__ void epi_store(
    f32x4* acc, unsigned short* __restrict__ Vb, int accum, int do_stats,
    float* ssum, float* ssq, int row0, int lr, int lq)
{
#pragma unroll
    for (int n = 0; n < 8; n++) {
        int col = n * 16 + lr;
        float s_ = 0.f, q_ = 0.f;
#pragma unroll
        for (int reg = 0; reg < 4; reg++) {
            int row = row0 + lq * 4 + reg;
            float v = acc[n][reg];
            unsigned short* vp = &Vb[(size_t)row * D128 + col];
            if (accum) v += bf2f(*vp);
            *vp = f2bf(v);
            s_ += v; q_ += v * v;
        }
        if (do_stats) {
            s_ += __shfl_xor(s_, 16); s_ += __shfl_xor(s_, 32);
            q_ += __shfl_xor(q_, 16); q_ += __shfl_xor(q_, 32);
            if (lq == 0) {
                atomicAdd(&ssum[col], s_);
                atomicAdd(&ssq[col], q_);
            }
        }
    }
}

// ---------------- single-output MFMA GEMM (W staged in LDS) ----------------
__global__ __launch_bounds__(256) void gemm_mfma(
    const unsigned short* __restrict__ A, const unsigned short* __restrict__ Wt,
    unsigned short* __restrict__ Vb, int accum, int do_stats, float* __restrict__ statsraw)
{
    __shared__ unsigned short lw[16384];
    __shared__ float ssum[128], ssq[128];
    int t = threadIdx.x;
    int wave = t >> 6, lane = t & 63;
    int lr = lane & 15, lq = lane >> 4;
    int row0 = blockIdx.x * 64 + wave * 16;

    if (t < 128) { ssum[t] = 0.f; ssq[t] = 0.f; }
    stage_w(Wt, lw, t);
    __syncthreads();

    f32x4 acc[8];
#pragma unroll
    for (int n = 0; n < 8; n++) acc[n] = (f32x4)(0.f);

    const unsigned short* arow = A + (size_t)(row0 + lr) * 128 + lq * 8;
#pragma unroll
    for (int kt = 0; kt < 4; kt++) {
        bf16x8 af = *(const bf16x8*)(arow + kt * 32);
#pragma unroll
        for (int n = 0; n < 8; n++) {
            bf16x8 bfr = read_w(lw, n * 16 + lr, kt, lq);
            acc[n] = __builtin_amdgcn_mfma_f32_16x16x32_bf16(af, bfr, acc[n], 0, 0, 0);
        }
    }
    epi_store(acc, Vb, accum, do_stats, ssum, ssq, row0, lr, lq);
    if (do_stats) {
        __syncthreads();
        if (t < 128) atomicAdd(&statsraw[t], ssum[t]);
        else atomicAdd(&statsraw[t], ssq[t - 128]);
    }
}

// ---------------- dual-output MFMA GEMM (A loaded once, both W in LDS) ----------------
__global__ __launch_bounds__(256) void gemm_mfma2(
    const unsigned short* __restrict__ A,
    const unsigned short* __restrict__ Wt0, const unsigned short* __restrict__ Wt1,
    unsigned short* __restrict__ V0b, unsigned short* __restrict__ V1b,
    int acc0f, int acc1f, int st0, int st1,
    float* __restrict__ sr0, float* __restrict__ sr1)
{
    __shared__ unsigned short lw0[16384], lw1[16384];
    __shared__ float ssum0[128], ssq0[128], ssum1[128], ssq1[128];
    int t = threadIdx.x;
    int wave = t >> 6, lane = t & 63;
    int lr = lane & 15, lq = lane >> 4;
    int row0 = blockIdx.x * 64 + wave * 16;

    if (t < 128) { ssum0[t] = 0.f; ssq0[t] = 0.f; ssum1[t] = 0.f; ssq1[t] = 0.f; }
    stage_w(Wt0, lw0, t);
    stage_w(Wt1, lw1, t);
    __syncthreads();

    f32x4 acc0[8], acc1[8];
#pragma unroll
    for (int n = 0; n < 8; n++) { acc0[n] = (f32x4)(0.f); acc1[n] = (f32x4)(0.f); }

    const unsigned short* arow = A + (size_t)(row0 + lr) * 128 + lq * 8;
#pragma unroll
    for (int kt = 0; kt < 4; kt++) {
        bf16x8 af = *(const bf16x8*)(arow + kt * 32);
#pragma unroll
        for (int n = 0; n < 8; n++) {
            int row = n * 16 + lr;
            bf16x8 b0 = read_w(lw0, row, kt, lq);
            bf16x8 b1 = read_w(lw1, row, kt, lq);
            acc0[n] = __builtin_amdgcn_mfma_f32_16x16x32_bf16(af, b0, acc0[n], 0, 0, 0);
            acc1[n] = __builtin_amdgcn_mfma_f32_16x16x32_bf16(af, b1, acc1[n], 0, 0, 0);
        }
    }
    epi_store(acc0, V0b, acc0f, st0, ssum0, ssq0, row0, lr, lq);
    epi_store(acc1, V1b, acc1f, st1, ssum1, ssq1, row0, lr, lq);
    __syncthreads();
    if (st0) {
        if (t < 128) atomicAdd(&sr0[t], ssum0[t]);
        else atomicAdd(&sr0[t], ssq0[t - 128]);
    }
    if (st1) {
        if (t < 128) atomicAdd(&sr1[t], ssum1[t]);
        else atomicAdd(&sr1[t], ssq1[t - 128]);
    }
}

struct FinArgs { int Ms[10]; };

__global__ void bn_finalize(const float* __restrict__ raw, float* __restrict__ fin, FinArgs fa)
{
    int tt = blockIdx.x;
    int c = threadIdx.x;
    float m = (float)fa.Ms[tt];
    float s = raw[tt * 256 + c], sq = raw[tt * 256 + 128 + c];
    float mu = s / m;
    float var = fmaxf(sq / m - mu * mu, 0.f);
    fin[tt * 256 + c] = mu;
    fin[tt * 256 + 128 + c] = rsqrtf(var + 1e-5f);
}

// ---------------- per-tensor attention score (L3-hot, inline BN stats) ----------------
__global__ __launch_bounds__(256) void attn_t(
    const unsigned short* __restrict__ Vb, const float* __restrict__ raw, float Minv,
    const float* __restrict__ gam, const float* __restrict__ bet,
    const float* __restrict__ pa,
    const unsigned short* __restrict__ W1t, const float* __restrict__ b1,
    const float* __restrict__ w2, float* __restrict__ Sout)
{
    __shared__ float st[256];
    __shared__ float red[4];
    int t = threadIdx.x;
    if (t < 128) {
        float mu = raw[t] * Minv;
        float var = fmaxf(raw[128 + t] * Minv - mu * mu, 0.f);
        st[t] = mu;
        st[128 + t] = rsqrtf(var + 1e-5f);
    }
    __syncthreads();

    int wave = t >> 6, lane = t & 63;
    int lr = lane & 15, lq = lane >> 4;
    int row0 = blockIdx.x * 64 + wave * 16;
    float a = *pa;

    f32x4 acc[8];
#pragma unroll
    for (int n = 0; n < 8; n++) acc[n] = (f32x4)(0.f);

    const unsigned short* vrow = Vb + (size_t)(row0 + lr) * D128;
#pragma unroll
    for (int kt = 0; kt < 4; kt++) {
        int k0 = kt * 32 + lq * 8;
        bf16x8 vv = *(const bf16x8*)(vrow + k0);
        bf16x8 af;
#pragma unroll
        for (int jj = 0; jj < 8; jj++) {
            int cc = k0 + jj;
            float y = bf2f((unsigned short)vv[jj]);
            float yy = gam[cc] * (y - st[cc]) * st[128 + cc] + bet[cc];
            yy = yy >= 0.f ? yy : a * yy;
            af[jj] = (short)f2bf(yy);
        }
#pragma unroll
        for (int n = 0; n < 8; n++) {
            bf16x8 bfr = *(const bf16x8*)(W1t + (size_t)(n * 16 + lr) * 128 + k0);
            acc[n] = __builtin_amdgcn_mfma_f32_16x16x32_bf16(af, bfr, acc[n], 0, 0, 0);
        }
    }

    float thr = 0.f;
#pragma unroll
    for (int n = 0; n < 8; n++) {
        int col = n * 16 + lr;
        float bc = b1[col], wc = w2[col];
#pragma unroll
        for (int reg = 0; reg < 4; reg++)
            thr += fast_tanh(acc[n][reg] + bc) * wc;
    }
#pragma unroll
    for (int off = 1; off < 64; off <<= 1)
        thr += __shfl_xor(thr, off);
    if (lane == 0) red[wave] = thr;
    __syncthreads();
    if (t == 0) atomicAdd(Sout, red[0] + red[1] + red[2] + red[3]);
}

// ---------------- all-pair combine (single launch, both sides bf16) ----------------
struct CombArgs {
    float* outp[5]; const unsigned short* va[5]; const unsigned short* vb[5];
    const float* stats; const float* gam; const float* bet; const float* pa; const float* S;
    int ta[5]; int tb[5]; int blka[5]; int blkb[5]; float invM[5]; int cum[6];
};

__global__ void combine_all(CombArgs D)
{
    int b = blockIdx.x, t = threadIdx.x;
    int p = 0;
    while (p < 4 && b >= D.cum[p + 1]) p++;
    size_t idx = (size_t)(b - D.cum[p]) * 256 + t;
    int c = (int)(idx & 127);
    float s0 = D.S[2 * p] * D.invM[p], s1 = D.S[2 * p + 1] * D.invM[p];
    float mx = fmaxf(s0, s1);
    float e0 = expf(s0 - mx), e1 = expf(s1 - mx);
    float inv = 1.f / (e0 + e1);
    float b0 = e0 * inv, b1w = e1 * inv;
    const float* sta = D.stats + D.ta[p] * 256;
    const float* stb = D.stats + D.tb[p] * 256;
    const float* ga = D.gam + D.blka[p] * 128;
    const float* ba = D.bet + D.blka[p] * 128;
    const float* gb = D.gam + D.blkb[p] * 128;
    const float* bb = D.bet + D.blkb[p] * 128;
    float aa = D.pa[D.blka[p]], ab = D.pa[D.blkb[p]];
    float va = bf2f(D.va[p][idx]);
    float vb = bf2f(D.vb[p][idx]);
    float ya = ga[c] * (va - sta[c]) * sta[128 + c] + ba[c];
    ya = ya >= 0.f ? ya : aa * ya;
    float yb = gb[c] * (vb - stb[c]) * stb[128 + c] + bb[c];
    yb = yb >= 0.f ? yb : ab * yb;
    D.outp[p][idx] = b0 * ya + b1w * yb;
}

// ---------------- host orchestration ----------------
extern "C" void kernel_launch(void* const* d_in, const int* in_sizes, int n_in,
                              void* d_out, int out_size, void* d_ws, size_t ws_size,
                              hipStream_t stream)
{
    const float* feats[5] = {
        (const float*)d_in[0], (const float*)d_in[1], (const float*)d_in[2],
        (const float*)d_in[3], (const float*)d_in[4]
    };
    const float* W_blocks = (const float*)d_in[25];
    const float* bn_gamma = (const float*)d_in[27];
    const float* bn_beta  = (const float*)d_in[28];
    const float* prelu_a  = (const float*)d_in[29];
    const float* attn_W1  = (const float*)d_in[30];
    const float* attn_b1  = (const float*)d_in[31];
    const float* attn_w2  = (const float*)d_in[32];
    float* out = (float*)d_out;

    // ---- d_out scratch (dead before combine writes): xbf | aggb ----
    unsigned* xbf  = (unsigned*)out;                    // 5,120,000 uints
    unsigned* aggb = (unsigned*)(out + 5120000);        // 5,120,000 uints

    // ---- workspace carve (4-byte slots) ----
    float* wsf = (float*)d_ws;
    unsigned short* wsvb = (unsigned short*)wsf;              // 71,680,000 bf16 = 35,840,000 slots
    unsigned short* wtbf = (unsigned short*)(wsf + 35840000); // 262,144 bf16 = 131,072 slots
    int* degs     = (int*)(wsf + 35971072);                   // 560,000
    int* histD    = degs + 560000;                            // 2194 x 80 = 175,520
    int* histS    = histD + 175520;                           // 2194 x 80 = 175,520
    int* colbaseD = histS + 175520;                           // 2,195
    int* totalsD  = colbaseD + 2195;                          // 2,194
    int* colbaseS = totalsD + 2194;                           // 2,195
    int* totalsS  = colbaseS + 2195;                          // 2,194
    int* epart    = totalsS + 2194;                           // 8,960,000
    unsigned char* spart = (unsigned char*)(epart + 8960000); // 8,960,000 bytes = 2,240,000 slots
    float* statsraw = (float*)(epart + 8960000 + 2240000);    // 2,560
    float* statsfin = statsraw + 2560;                        // 2,560
    float* Ssum     = statsfin + 2560;                        // 16
    size_t needed = ((size_t)((float*)(Ssum + 16) - wsf)) * 4;
    if (ws_size < needed) return;

    // tensors: T0 d0, T1 d1, T2 dis0, T3 dis4, T4 p1, T5 p2, T6 g2, T7 g3, T8 pw3, T9 pw4
    const int Mt[10]  = {40000, 40000, 40000, 40000, 80000, 80000, 80000, 80000, 40000, 40000};
    const int blk[10] = {0, 1, 0, 4, 1, 2, 2, 3, 3, 4};
    size_t offV[10];
    {
        size_t o = 0;
        for (int t = 0; t < 10; t++) { offV[t] = o; o += (size_t)Mt[t] * 128; }
    }
    unsigned short* Vb[10];
    for (int t = 0; t < 10; t++) Vb[t] = wsvb + offV[t];
    const size_t offT[5] = {0, 5120000, 10240000, 20480000, 30720000};

    // rel order: dd, ddi, dp, disdis, pp, pg, gg, gpw, pwpw, pwdis
    const int relFeat[10] = {0, 0, 0, 1, 2, 2, 3, 3, 4, 4};
    const int relSrc[10]  = {5, 7, 11, 9, 13, 15, 17, 19, 21, 23};
    const int relNs[10]   = {40000, 40000, 40000, 40000, 80000, 80000, 80000, 80000, 40000, 40000};
    const int relNd[10]   = {40000, 40000, 80000, 40000, 80000, 80000, 80000, 40000, 40000, 40000};
    const int relE[10]    = {640000, 640000, 640000, 640000, 1280000,
                             1280000, 1280000, 1280000, 640000, 640000};
    // 16384 edges per block: 640k->40, 1.28M->79
    const int cumBlk[11]  = {0, 40, 80, 120, 160, 239, 318, 397, 476, 516, 556};
    // dst buckets 256-wide: 40000->157, 80000->313 (per relNd)
    const int dstColBase[11] = {0, 157, 314, 627, 784, 1097, 1410, 1723, 1880, 2037, 2194};
    // src buckets 256-wide (per relNs)
    const int srcColBase[11] = {0, 157, 314, 471, 628, 941, 1254, 1567, 1880, 2037, 2194};
    const int degsBase[10]   = {0, 40000, 80000, 120000, 160000, 240000, 320000, 400000, 480000, 520000};

    struct GJob { int tid; int widx; int accum; int stats; };
    const int relNjob[10] = {2, 1, 1, 2, 2, 1, 2, 1, 2, 1};
    const GJob relJob[10][2] = {
        {{0,  0, 0, 1}, {1,  3, 0, 1}},  // dd      -> completes T0, T1
        {{2,  1, 0, 0}, {0,  0, 0, 0}},  // ddi
        {{4,  4, 0, 0}, {0,  0, 0, 0}},  // dp
        {{2,  2, 1, 1}, {3, 14, 0, 0}},  // disdis  -> completes T2
        {{4,  5, 1, 1}, {5,  6, 0, 1}},  // pp      -> completes T4, T5
        {{6,  7, 0, 0}, {0,  0, 0, 0}},  // pg
        {{6,  8, 1, 1}, {7,  9, 0, 1}},  // gg      -> completes T6, T7
        {{8, 10, 0, 0}, {0,  0, 0, 0}},  // gpw
        {{8, 11, 1, 1}, {9, 12, 0, 1}},  // pwpw    -> completes T8, T9
        {{3, 13, 1, 1}, {0,  0, 0, 0}},  // pwdis   -> completes T3
    };
    const int doneCnt[10] = {2, 0, 0, 1, 2, 0, 2, 0, 2, 1};
    const int doneT[10][2] = {{0,1},{0,0},{0,0},{2,0},{4,5},{0,0},{6,7},{0,0},{8,9},{3,0}};

    // ---- one-time conversions & zeroing ----
    wconv_t<<<16, 256, 0, stream>>>(W_blocks, attn_W1, wtbf);
    hipMemsetAsync(statsraw, 0, (2560 + 2560 + 16) * sizeof(float), stream);

    // ---- batched partitioned CSR build ----
    BuildArgs BA;
    ScanArgs  SAD, SAS;
    ScatArgs  CA;
    DegArgs   DA;
    for (int r = 0; r < 10; r++) {
        BA.esrc[r] = (const int*)d_in[relSrc[r]];
        BA.edst[r] = (const int*)d_in[relSrc[r] + 1];
        BA.E[r] = relE[r];
        CA.esrc[r] = BA.esrc[r]; CA.edst[r] = BA.edst[r]; CA.E[r] = relE[r];
        DA.degsBase[r] = degsBase[r];
        DA.ns[r] = relNs[r];
    }
    for (int i = 0; i < 11; i++) {
        BA.cumBlk[i] = cumBlk[i]; BA.dstColBase[i] = dstColBase[i]; BA.srcColBase[i] = srcColBase[i];
        SAD.colBase[i] = dstColBase[i]; SAD.cumBlk[i] = cumBlk[i];
        SAS.colBase[i] = srcColBase[i]; SAS.cumBlk[i] = cumBlk[i];
        CA.cumBlk[i] = cumBlk[i]; CA.dstColBase[i] = dstColBase[i]; CA.srcColBase[i] = srcColBase[i];
        DA.colBase[i] = srcColBase[i];
    }
    BA.histD = histD; BA.histS = histS;
    SAD.hist = histD; SAD.totals = totalsD;
    SAS.hist = histS; SAS.totals = totalsS;
    CA.histD = histD; CA.colbaseD = colbaseD;
    CA.histS = histS; CA.colbaseS = colbaseS;
    CA.epart = epart; CA.spart = spart;
    DA.spart = spart; DA.colbase = colbaseS; DA.degs = degs;

    part_count<<<556, 256, 0, stream>>>(BA);
    col_scan<<<2194, 256, 0, stream>>>(SAD);
    col_scan<<<2194, 256, 0, stream>>>(SAS);
    base_scan<<<1, 256, 0, stream>>>(totalsD, colbaseD, 2194);
    base_scan<<<1, 256, 0, stream>>>(totalsS, colbaseS, 2194);
    scatter_all<<<556, 256, 0, stream>>>(CA);
    deg_count<<<2194, 256, 0, stream>>>(DA);

    // ---- per-rel scaled-xconv + fused bucket-gather + GEMM + L3-hot attention ----
    for (int r = 0; r < 10; r++) {
        xconv_scaled<<<(relNs[r] + 3) / 4, 256, 0, stream>>>(
            feats[relFeat[r]], degs + degsBase[r], xbf, relNs[r]);
        int nbuck = dstColBase[r + 1] - dstColBase[r];
        bucket_gather<<<nbuck, 256, 0, stream>>>(
            xbf, epart, colbaseD, dstColBase[r], aggb, relNd[r]);
        if (relNjob[r] == 2) {
            const GJob& G0 = relJob[r][0];
            const GJob& G1 = relJob[r][1];
            gemm_mfma2<<<relNd[r] / 64, 256, 0, stream>>>(
                (const unsigned short*)aggb,
                wtbf + (size_t)G0.widx * 16384, wtbf + (size_t)G1.widx * 16384,
                Vb[G0.tid], Vb[G1.tid], G0.accum, G1.accum, G0.stats, G1.stats,
                statsraw + (size_t)G0.tid * 256, statsraw + (size_t)G1.tid * 256);
        } else {
            const GJob& G = relJob[r][0];
            gemm_mfma<<<relNd[r] / 64, 256, 0, stream>>>(
                (const unsigned short*)aggb, wtbf + (size_t)G.widx * 16384,
                Vb[G.tid], G.accum, G.stats, statsraw + (size_t)G.tid * 256);
        }
        for (int k = 0; k < doneCnt[r]; k++) {
            int t = doneT[r][k];
            attn_t<<<Mt[t] / 64, 256, 0, stream>>>(
                Vb[t], statsraw + (size_t)t * 256, 1.0f / Mt[t],
                bn_gamma + blk[t] * 128, bn_beta + blk[t] * 128, prelu_a + blk[t],
                wtbf + (size_t)15 * 16384, attn_b1, attn_w2, Ssum + t);
        }
    }

    FinArgs fa;
    for (int t = 0; t < 10; t++) fa.Ms[t] = Mt[t];
    bn_finalize<<<10, 128, 0, stream>>>(statsraw, statsfin, fa);

    CombArgs CD;
    CD.stats = statsfin; CD.gam = bn_gamma; CD.bet = bn_beta; CD.pa = prelu_a; CD.S = Ssum;
    CD.cum[0] = 0;
    for (int p = 0; p < 5; p++) {
        CD.outp[p] = out + offT[p];
        CD.va[p] = Vb[p * 2];
        CD.vb[p] = Vb[p * 2 + 1];
        CD.ta[p] = p * 2; CD.tb[p] = p * 2 + 1;
        CD.blka[p] = blk[p * 2]; CD.blkb[p] = blk[p * 2 + 1];
        CD.invM[p] = 1.0f / Mt[p * 2];
        CD.cum[p + 1] = CD.cum[p] + Mt[p * 2] / 2;
    }
    combine_all<<<CD.cum[5], 256, 0, stream>>>(CD);
}

// Round 19
// 1505.069 us; speedup vs baseline: 1.6744x; 1.6744x over previous
//
#include <hip/hip_runtime.h>
#include <hip/hip_bf16.h>

#define D128 128
#define STAGE 12288

typedef __attribute__((ext_vector_type(8))) short bf16x8;
typedef __attribute__((ext_vector_type(4))) float f32x4;

__device__ inline unsigned short f2bf(float f) {
    unsigned u = __float_as_uint(f);
    u = u + 0x7fffu + ((u >> 16) & 1u);
    return (unsigned short)(u >> 16);
}
__device__ inline float bf2f(unsigned short h) {
    return __uint_as_float(((unsigned)h) << 16);
}
__device__ inline float fast_tanh(float x) {
    float e = __expf(2.f * x);
    return 1.f - 2.f * __builtin_amdgcn_rcpf(e + 1.f);
}

// stage a 128x128 bf16 W into LDS with 16B-slot XOR swizzle (slot ^= row&7)
__device__ __forceinline__ void stage_w(const unsigned short* __restrict__ Wt,
                                        unsigned short* lw, int t)
{
    const uint4* srcW = (const uint4*)Wt;
    uint4* dstW = (uint4*)lw;
    for (int i = t; i < 2048; i += 256) {
        int row = i >> 4, sl = i & 15;
        dstW[row * 16 + (sl ^ (row & 7))] = srcW[i];
    }
}
__device__ __forceinline__ bf16x8 read_w(const unsigned short* lw, int row, int kt, int lq)
{
    int slot = (kt * 4 + lq) ^ (row & 7);
    return *(const bf16x8*)(lw + row * 128 + slot * 8);
}

// wave-parallel exclusive scan of arr[0..n) into ofs[0..n], one 64-lane wave
__device__ __forceinline__ void wave_scan(const int* arr, int* ofs, int n, int lane)
{
    int k = (n + 63) >> 6;
    int base = lane * k;
    int sum = 0;
    for (int i = 0; i < k; i++) { int idx = base + i; if (idx < n) sum += arr[idx]; }
    int pre = sum;
    for (int off = 1; off < 64; off <<= 1) {
        int u = __shfl(pre, (lane - off) & 63);
        if (lane >= off) pre += u;
    }
    int run = pre - sum;
    for (int i = 0; i < k; i++) { int idx = base + i; if (idx < n) { ofs[idx] = run; run += arr[idx]; } }
    if (lane == 63) ofs[n] = run;
}

// ---------------- per-rel pre-scaled bf16 feature conversion ----------------
__global__ __launch_bounds__(256) void xconv_scaled(
    const float* __restrict__ in, const int* __restrict__ degs,
    unsigned* __restrict__ out, int nrows)
{
    int t = threadIdx.x;
    int lane = t & 63, rr = t >> 6;
    int row = blockIdx.x * 4 + rr;
    if (row >= nrows) return;
    float sc = rsqrtf((float)max(degs[row], 1));
    float2 v = ((const float2*)(in + (size_t)row * 128))[lane];
    out[(size_t)row * 64 + lane] =
        (unsigned)f2bf(v.x * sc) | ((unsigned)f2bf(v.y * sc) << 16);
}

// ---------------- weight transpose + convert: Wt[n][k] = W[k][n] ----------------
__global__ void wconv_t(const float* __restrict__ W_blocks, const float* __restrict__ W1,
                        unsigned short* __restrict__ wt)
{
    int m = blockIdx.x;  // 0..15
    const float* src = (m < 15) ? (W_blocks + (size_t)m * 16384) : W1;
    unsigned short* dst = wt + (size_t)m * 16384;
    for (int i = threadIdx.x; i < 16384; i += 256) {
        int n = i >> 7, k = i & 127;
        dst[i] = f2bf(src[k * 128 + n]);
    }
}

// ================= partitioned CSR build (16384 edges/block; 256-wide buckets) ==========
struct BuildArgs {
    const int* esrc[10]; const int* edst[10];
    int* histD; int* histS;
    int cumBlk[11]; int dstColBase[11]; int srcColBase[11]; int E[10];
};

__global__ __launch_bounds__(256) void part_count(BuildArgs A)
{
    __shared__ int hd[320], hs[320];
    int blk = blockIdx.x, t = threadIdx.x;
    int r = 0;
    while (r < 9 && blk >= A.cumBlk[r + 1]) r++;
    int blkInRel = blk - A.cumBlk[r];
    int nbD = A.dstColBase[r + 1] - A.dstColBase[r];
    int nbS = A.srcColBase[r + 1] - A.srcColBase[r];
    for (int i = t; i < nbD; i += 256) hd[i] = 0;
    for (int i = t; i < nbS; i += 256) hs[i] = 0;
    __syncthreads();
    int e0 = blkInRel * 16384;
    const int* sp = A.esrc[r];
    const int* dp = A.edst[r];
    int E = A.E[r];
#pragma unroll 4
    for (int j = 0; j < 64; j++) {
        int e = e0 + j * 256 + t;
        if (e < E) {
            atomicAdd(&hd[dp[e] >> 8], 1);
            atomicAdd(&hs[sp[e] >> 8], 1);
        }
    }
    __syncthreads();
    int cd = A.dstColBase[r], cs = A.srcColBase[r];
    for (int i = t; i < nbD; i += 256)
        A.histD[(size_t)(cd + i) * 80 + blkInRel] = hd[i];
    for (int i = t; i < nbS; i += 256)
        A.histS[(size_t)(cs + i) * 80 + blkInRel] = hs[i];
}

struct ScanArgs { int* hist; int* totals; int colBase[11]; int cumBlk[11]; };

__global__ __launch_bounds__(256) void col_scan(ScanArgs A)
{
    __shared__ int v[80];
    int col = blockIdx.x, t = threadIdx.x;
    int r = 0;
    while (r < 9 && col >= A.colBase[r + 1]) r++;
    int nblk = A.cumBlk[r + 1] - A.cumBlk[r];
    for (int i = t; i < nblk; i += 256) v[i] = A.hist[(size_t)col * 80 + i];
    __syncthreads();
    if (t == 0) {
        int run = 0;
        for (int i = 0; i < nblk; i++) { int c = v[i]; v[i] = run; run += c; }
        A.totals[col] = run;
    }
    __syncthreads();
    for (int i = t; i < nblk; i += 256) A.hist[(size_t)col * 80 + i] = v[i];
}

__global__ __launch_bounds__(256) void base_scan(const int* __restrict__ totals,
                                                 int* __restrict__ colbase, int n)
{
    __shared__ int v[2200];
    int t = threadIdx.x;
    for (int i = t; i < n; i += 256) v[i] = totals[i];
    __syncthreads();
    if (t == 0) {
        int run = 0;
        for (int i = 0; i < n; i++) { int c = v[i]; v[i] = run; run += c; }
        v[n] = run;
    }
    __syncthreads();
    for (int i = t; i <= n; i += 256) colbase[i] = v[i];
}

// fused scatter with chunked LDS staging: bucket-sorted flushes, contiguous cursors
struct ScatArgs {
    const int* esrc[10]; const int* edst[10];
    const int* histD; const int* colbaseD;
    const int* histS; const int* colbaseS;
    int* epart; unsigned char* spart;
    int cumBlk[11]; int dstColBase[11]; int srcColBase[11]; int E[10];
};

__global__ __launch_bounds__(256) void scatter_all(ScatArgs A)
{
    __shared__ int stageE[4096];
    __shared__ unsigned short bidE[4096];
    __shared__ unsigned short bidS[4096];
    __shared__ unsigned char stageS[4096];
    __shared__ int gbaseD[320], gcurD[320], lhistD[320], lofsD[321];
    __shared__ int gbaseS[320], gcurS[320], lhistS[320], lofsS[321];

    int blk = blockIdx.x, t = threadIdx.x;
    int r = 0;
    while (r < 9 && blk >= A.cumBlk[r + 1]) r++;
    int blkInRel = blk - A.cumBlk[r];
    int cd = A.dstColBase[r], cs = A.srcColBase[r];
    int nbD = A.dstColBase[r + 1] - cd;
    int nbS = A.srcColBase[r + 1] - cs;
    for (int i = t; i < nbD; i += 256) {
        gbaseD[i] = A.colbaseD[cd + i] + A.histD[(size_t)(cd + i) * 80 + blkInRel];
        gcurD[i] = 0;
    }
    for (int i = t; i < nbS; i += 256) {
        gbaseS[i] = A.colbaseS[cs + i] + A.histS[(size_t)(cs + i) * 80 + blkInRel];
        gcurS[i] = 0;
    }
    const int* sp = A.esrc[r];
    const int* dp = A.edst[r];
    int E = A.E[r];
    int blkbase = blkInRel * 16384;

    for (int c = 0; c < 4; c++) {
        int e0 = blkbase + c * 4096;
        int sv[16], dv[16];
#pragma unroll
        for (int j = 0; j < 16; j++) {
            int e = e0 + j * 256 + t;
            sv[j] = (e < E) ? sp[e] : -1;
            dv[j] = (e < E) ? dp[e] : 0;
        }
        for (int i = t; i < nbD; i += 256) lhistD[i] = 0;
        for (int i = t; i < nbS; i += 256) lhistS[i] = 0;
        __syncthreads();
#pragma unroll
        for (int j = 0; j < 16; j++) {
            if (sv[j] >= 0) {
                atomicAdd(&lhistD[dv[j] >> 8], 1);
                atomicAdd(&lhistS[sv[j] >> 8], 1);
            }
        }
        __syncthreads();
        if (t < 64) wave_scan(lhistD, lofsD, nbD, t);
        else if (t < 128) wave_scan(lhistS, lofsS, nbS, t - 64);
        __syncthreads();
        for (int i = t; i < nbD; i += 256) lhistD[i] = 0;
        for (int i = t; i < nbS; i += 256) lhistS[i] = 0;
        __syncthreads();
#pragma unroll
        for (int j = 0; j < 16; j++) {
            if (sv[j] >= 0) {
                int bd = dv[j] >> 8;
                int p = atomicAdd(&lhistD[bd], 1);
                int ix = lofsD[bd] + p;
                stageE[ix] = (sv[j] & 0x1FFFF) | ((dv[j] & 255) << 17);
                bidE[ix] = (unsigned short)bd;
                int bs = sv[j] >> 8;
                int q = atomicAdd(&lhistS[bs], 1);
                int iy = lofsS[bs] + q;
                stageS[iy] = (unsigned char)(sv[j] & 255);
                bidS[iy] = (unsigned short)bs;
            }
        }
        __syncthreads();
        int cntv = lofsD[nbD];
        for (int i = t; i < cntv; i += 256) {
            int b = bidE[i];
            A.epart[gbaseD[b] + gcurD[b] + i - lofsD[b]] = stageE[i];
        }
        for (int i = t; i < cntv; i += 256) {
            int b = bidS[i];
            A.spart[(size_t)gbaseS[b] + gcurS[b] + i - lofsS[b]] = stageS[i];
        }
        __syncthreads();
        for (int i = t; i < nbD; i += 256) gcurD[i] += lofsD[i + 1] - lofsD[i];
        for (int i = t; i < nbS; i += 256) gcurS[i] += lofsS[i + 1] - lofsS[i];
        __syncthreads();
    }
}

// per-256-src-bucket degree count
struct DegArgs {
    const unsigned char* spart; const int* colbase;
    int* degs;
    int colBase[11]; int degsBase[10]; int ns[10];
};

__global__ __launch_bounds__(256) void deg_count(DegArgs A)
{
    __shared__ int lc[256];
    int col = blockIdx.x, t = threadIdx.x;
    int r = 0;
    while (r < 9 && col >= A.colBase[r + 1]) r++;
    int b = col - A.colBase[r];
    lc[t] = 0;
    __syncthreads();
    int start = A.colbase[col], end = A.colbase[col + 1];
    for (int i = start + t; i < end; i += 256)
        atomicAdd(&lc[A.spart[i]], 1);
    __syncthreads();
    int s = b * 256 + t;
    if (s < A.ns[r]) A.degs[A.degsBase[r] + s] = lc[t];
}

// ---------------- per-bucket LDS counting sort -> packed CSR (coalesced writes) -------
struct SortArgs {
    const int* epart; const int* colbase;
    int* csrE; int* rowStart; int* rowCnt;
    int dstColBase[11]; int cursorBase[10]; int nd[10];
};

__global__ __launch_bounds__(256) void bucket_sort(SortArgs A)
{
    __shared__ int stage[STAGE];
    __shared__ int lhist[256], lofs[257];
    int col = blockIdx.x, t = threadIdx.x;
    int r = 0;
    while (r < 9 && col >= A.dstColBase[r + 1]) r++;
    int b = col - A.dstColBase[r];
    int start = A.colbase[col], end = A.colbase[col + 1];
    int total = end - start;
    int main_ = min(total, STAGE);

    lhist[t] = 0;
    __syncthreads();
    for (int i = t; i < main_; i += 256)
        atomicAdd(&lhist[(A.epart[start + i] >> 17) & 255], 1);
    __syncthreads();
    if (t < 64) wave_scan(lhist, lofs, 256, t);
    __syncthreads();
    lhist[t] = 0;
    __syncthreads();
    for (int i = t; i < main_; i += 256) {
        int v = A.epart[start + i];
        int b8 = (v >> 17) & 255;
        int p = atomicAdd(&lhist[b8], 1);
        stage[lofs[b8] + p] = v & 0x1FFFF;
    }
    __syncthreads();
    for (int i = t; i < main_; i += 256)
        A.csrE[start + i] = stage[i];
    int d = b * 256 + t;
    if (d < A.nd[r]) {
        A.rowStart[A.cursorBase[r] + d] = start + lofs[t];
        A.rowCnt[A.cursorBase[r] + d] = lofs[t + 1] - lofs[t];
    }
}

// ---------------- bf16 CSR gather over packed rows (X pre-scaled) ----------------
__global__ __launch_bounds__(256) void gather_bf16(
    const unsigned* __restrict__ Xb,
    const int* __restrict__ rowStart, const int* __restrict__ rowCnt,
    const int* __restrict__ csrE, const int* __restrict__ epart,
    const int* __restrict__ colbase, int colBase0,
    unsigned* __restrict__ aggb, int nd)
{
    int t = threadIdx.x;
    int lane = t & 63, r = t >> 6;
    int d = blockIdx.x * 4 + r;
    if (d >= nd) return;
    int st = rowStart[d];
    int cnt = rowCnt[d];
    const int* eb = csrE + st;
    float a0 = 0.f, a1 = 0.f;
    int i = 0;
    for (; i + 4 <= cnt; i += 4) {
        int s0 = eb[i], s1 = eb[i + 1], s2 = eb[i + 2], s3 = eb[i + 3];
        unsigned x0 = Xb[(size_t)s0 * 64 + lane];
        unsigned x1 = Xb[(size_t)s1 * 64 + lane];
        unsigned x2 = Xb[(size_t)s2 * 64 + lane];
        unsigned x3 = Xb[(size_t)s3 * 64 + lane];
        a0 += bf2f((unsigned short)(x0 & 0xffff)) + bf2f((unsigned short)(x1 & 0xffff))
            + bf2f((unsigned short)(x2 & 0xffff)) + bf2f((unsigned short)(x3 & 0xffff));
        a1 += bf2f((unsigned short)(x0 >> 16)) + bf2f((unsigned short)(x1 >> 16))
            + bf2f((unsigned short)(x2 >> 16)) + bf2f((unsigned short)(x3 >> 16));
    }
    for (; i < cnt; i++) {
        int s0 = eb[i];
        unsigned x0 = Xb[(size_t)s0 * 64 + lane];
        a0 += bf2f((unsigned short)(x0 & 0xffff));
        a1 += bf2f((unsigned short)(x0 >> 16));
    }
    // astronomically-rare unsorted tail (bucket exceeded STAGE): scan packed epart
    int col = colBase0 + (d >> 8);
    int s0c = colbase[col], e0c = colbase[col + 1];
    int tot = cnt;
    if (e0c - s0c > STAGE) {
        for (int j = s0c + STAGE; j < e0c; j++) {
            int v = epart[j];
            if (((v >> 17) & 255) == (d & 255)) {
                int s0 = v & 0x1FFFF;
                unsigned x0 = Xb[(size_t)s0 * 64 + lane];
                a0 += bf2f((unsigned short)(x0 & 0xffff));
                a1 += bf2f((unsigned short)(x0 >> 16));
                tot++;
            }
        }
    }
    float sc = rsqrtf((float)max(tot, 1));
    a0 *= sc; a1 *= sc;
    aggb[(size_t)d * 64 + lane] = (unsigned)f2bf(a0) | ((unsigned)f2bf(a1) << 16);
}

// ---------------- GEMM epilogue: bf16 store + fused BN stats ----------------
__device__ __forceinline__ void epi_store(
    f32x4* acc, unsigned short* __restrict__ Vb, int accum, int do_stats,
    float* ssum, float* ssq, int row0, int lr, int lq)
{
#pragma unroll
    for (int n = 0; n < 8; n++) {
        int col = n * 16 + lr;
        float s_ = 0.f, q_ = 0.f;
#pragma unroll
        for (int reg = 0; reg < 4; reg++) {
            int row = row0 + lq * 4 + reg;
            float v = acc[n][reg];
            unsigned short* vp = &Vb[(size_t)row * D128 + col];
            if (accum) v += bf2f(*vp);
            *vp = f2bf(v);
            s_ += v; q_ += v * v;
        }
        if (do_stats) {
            s_ += __shfl_xor(s_, 16); s_ += __shfl_xor(s_, 32);
            q_ += __shfl_xor(q_, 16); q_ += __shfl_xor(q_, 32);
            if (lq == 0) {
                atomicAdd(&ssum[col], s_);
                atomicAdd(&ssq[col], q_);
            }
        }
    }
}

// ---------------- single-output MFMA GEMM (W staged in LDS) ----------------
__global__ __launch_bounds__(256) void gemm_mfma(
    const unsigned short* __restrict__ A, const unsigned short* __restrict__ Wt,
    unsigned short* __restrict__ Vb, int accum, int do_stats, float* __restrict__ statsraw)
{
    __shared__ unsigned short lw[16384];
    __shared__ float ssum[128], ssq[128];
    int t = threadIdx.x;
    int wave = t >> 6, lane = t & 63;
    int lr = lane & 15, lq = lane >> 4;
    int row0 = blockIdx.x * 64 + wave * 16;

    if (t < 128) { ssum[t] = 0.f; ssq[t] = 0.f; }
    stage_w(Wt, lw, t);
    __syncthreads();

    f32x4 acc[8];
#pragma unroll
    for (int n = 0; n < 8; n++) acc[n] = (f32x4)(0.f);

    const unsigned short* arow = A + (size_t)(row0 + lr) * 128 + lq * 8;
#pragma unroll
    for (int kt = 0; kt < 4; kt++) {
        bf16x8 af = *(const bf16x8*)(arow + kt * 32);
#pragma unroll
        for (int n = 0; n < 8; n++) {
            bf16x8 bfr = read_w(lw, n * 16 + lr, kt, lq);
            acc[n] = __builtin_amdgcn_mfma_f32_16x16x32_bf16(af, bfr, acc[n], 0, 0, 0);
        }
    }
    epi_store(acc, Vb, accum, do_stats, ssum, ssq, row0, lr, lq);
    if (do_stats) {
        __syncthreads();
        if (t < 128) atomicAdd(&statsraw[t], ssum[t]);
        else atomicAdd(&statsraw[t], ssq[t - 128]);
    }
}

// ---------------- dual-output MFMA GEMM (A loaded once, both W in LDS) ----------------
__global__ __launch_bounds__(256) void gemm_mfma2(
    const unsigned short* __restrict__ A,
    const unsigned short* __restrict__ Wt0, const unsigned short* __restrict__ Wt1,
    unsigned short* __restrict__ V0b, unsigned short* __restrict__ V1b,
    int acc0f, int acc1f, int st0, int st1,
    float* __restrict__ sr0, float* __restrict__ sr1)
{
    __shared__ unsigned short lw0[16384], lw1[16384];
    __shared__ float ssum0[128], ssq0[128], ssum1[128], ssq1[128];
    int t = threadIdx.x;
    int wave = t >> 6, lane = t & 63;
    int lr = lane & 15, lq = lane >> 4;
    int row0 = blockIdx.x * 64 + wave * 16;

    if (t < 128) { ssum0[t] = 0.f; ssq0[t] = 0.f; ssum1[t] = 0.f; ssq1[t] = 0.f; }
    stage_w(Wt0, lw0, t);
    stage_w(Wt1, lw1, t);
    __syncthreads();

    f32x4 acc0[8], acc1[8];
#pragma unroll
    for (int n = 0; n < 8; n++) { acc0[n] = (f32x4)(0.f); acc1[n] = (f32x4)(0.f); }

    const unsigned short* arow = A + (size_t)(row0 + lr) * 128 + lq * 8;
#pragma unroll
    for (int kt = 0; kt < 4; kt++) {
        bf16x8 af = *(const bf16x8*)(arow + kt * 32);
#pragma unroll
        for (int n = 0; n < 8; n++) {
            int row = n * 16 + lr;
            bf16x8 b0 = read_w(lw0, row, kt, lq);
            bf16x8 b1 = read_w(lw1, row, kt, lq);
            acc0[n] = __builtin_amdgcn_mfma_f32_16x16x32_bf16(af, b0, acc0[n], 0, 0, 0);
            acc1[n] = __builtin_amdgcn_mfma_f32_16x16x32_bf16(af, b1, acc1[n], 0, 0, 0);
        }
    }
    epi_store(acc0, V0b, acc0f, st0, ssum0, ssq0, row0, lr, lq);
    epi_store(acc1, V1b, acc1f, st1, ssum1, ssq1, row0, lr, lq);
    __syncthreads();
    if (st0) {
        if (t < 128) atomicAdd(&sr0[t], ssum0[t]);
        else atomicAdd(&sr0[t], ssq0[t - 128]);
    }
    if (st1) {
        if (t < 128) atomicAdd(&sr1[t], ssum1[t]);
        else atomicAdd(&sr1[t], ssq1[t - 128]);
    }
}

struct FinArgs { int Ms[10]; };

__global__ void bn_finalize(const float* __restrict__ raw, float* __restrict__ fin, FinArgs fa)
{
    int tt = blockIdx.x;
    int c = threadIdx.x;
    float m = (float)fa.Ms[tt];
    float s = raw[tt * 256 + c], sq = raw[tt * 256 + 128 + c];
    float mu = s / m;
    float var = fmaxf(sq / m - mu * mu, 0.f);
    fin[tt * 256 + c] = mu;
    fin[tt * 256 + 128 + c] = rsqrtf(var + 1e-5f);
}

// ---------------- per-tensor attention score (L3-hot, inline BN stats) ----------------
__global__ __launch_bounds__(256) void attn_t(
    const unsigned short* __restrict__ Vb, const float* __restrict__ raw, float Minv,
    const float* __restrict__ gam, const float* __restrict__ bet,
    const float* __restrict__ pa,
    const unsigned short* __restrict__ W1t, const float* __restrict__ b1,
    const float* __restrict__ w2, float* __restrict__ Sout)
{
    __shared__ float st[256];
    __shared__ float red[4];
    int t = threadIdx.x;
    if (t < 128) {
        float mu = raw[t] * Minv;
        float var = fmaxf(raw[128 + t] * Minv - mu * mu, 0.f);
        st[t] = mu;
        st[128 + t] = rsqrtf(var + 1e-5f);
    }
    __syncthreads();

    int wave = t >> 6, lane = t & 63;
    int lr = lane & 15, lq = lane >> 4;
    int row0 = blockIdx.x * 64 + wave * 16;
    float a = *pa;

    f32x4 acc[8];
#pragma unroll
    for (int n = 0; n < 8; n++) acc[n] = (f32x4)(0.f);

    const unsigned short* vrow = Vb + (size_t)(row0 + lr) * D128;
#pragma unroll
    for (int kt = 0; kt < 4; kt++) {
        int k0 = kt * 32 + lq * 8;
        bf16x8 vv = *(const bf16x8*)(vrow + k0);
        bf16x8 af;
#pragma unroll
        for (int jj = 0; jj < 8; jj++) {
            int cc = k0 + jj;
            float y = bf2f((unsigned short)vv[jj]);
            float yy = gam[cc] * (y - st[cc]) * st[128 + cc] + bet[cc];
            yy = yy >= 0.f ? yy : a * yy;
            af[jj] = (short)f2bf(yy);
        }
#pragma unroll
        for (int n = 0; n < 8; n++) {
            bf16x8 bfr = *(const bf16x8*)(W1t + (size_t)(n * 16 + lr) * 128 + k0);
            acc[n] = __builtin_amdgcn_mfma_f32_16x16x32_bf16(af, bfr, acc[n], 0, 0, 0);
        }
    }

    float thr = 0.f;
#pragma unroll
    for (int n = 0; n < 8; n++) {
        int col = n * 16 + lr;
        float bc = b1[col], wc = w2[col];
#pragma unroll
        for (int reg = 0; reg < 4; reg++)
            thr += fast_tanh(acc[n][reg] + bc) * wc;
    }
#pragma unroll
    for (int off = 1; off < 64; off <<= 1)
        thr += __shfl_xor(thr, off);
    if (lane == 0) red[wave] = thr;
    __syncthreads();
    if (t == 0) atomicAdd(Sout, red[0] + red[1] + red[2] + red[3]);
}

// ---------------- all-pair combine (single launch, both sides bf16) ----------------
struct CombArgs {
    float* outp[5]; const unsigned short* va[5]; const unsigned short* vb[5];
    const float* stats; const float* gam; const float* bet; const float* pa; const float* S;
    int ta[5]; int tb[5]; int blka[5]; int blkb[5]; float invM[5]; int cum[6];
};

__global__ void combine_all(CombArgs D)
{
    int b = blockIdx.x, t = threadIdx.x;
    int p = 0;
    while (p < 4 && b >= D.cum[p + 1]) p++;
    size_t idx = (size_t)(b - D.cum[p]) * 256 + t;
    int c = (int)(idx & 127);
    float s0 = D.S[2 * p] * D.invM[p], s1 = D.S[2 * p + 1] * D.invM[p];
    float mx = fmaxf(s0, s1);
    float e0 = expf(s0 - mx), e1 = expf(s1 - mx);
    float inv = 1.f / (e0 + e1);
    float b0 = e0 * inv, b1w = e1 * inv;
    const float* sta = D.stats + D.ta[p] * 256;
    const float* stb = D.stats + D.tb[p] * 256;
    const float* ga = D.gam + D.blka[p] * 128;
    const float* ba = D.bet + D.blka[p] * 128;
    const float* gb = D.gam + D.blkb[p] * 128;
    const float* bb = D.bet + D.blkb[p] * 128;
    float aa = D.pa[D.blka[p]], ab = D.pa[D.blkb[p]];
    float va = bf2f(D.va[p][idx]);
    float vb = bf2f(D.vb[p][idx]);
    float ya = ga[c] * (va - sta[c]) * sta[128 + c] + ba[c];
    ya = ya >= 0.f ? ya : aa * ya;
    float yb = gb[c] * (vb - stb[c]) * stb[128 + c] + bb[c];
    yb = yb >= 0.f ? yb : ab * yb;
    D.outp[p][idx] = b0 * ya + b1w * yb;
}

// ---------------- host orchestration ----------------
extern "C" void kernel_launch(void* const* d_in, const int* in_sizes, int n_in,
                              void* d_out, int out_size, void* d_ws, size_t ws_size,
                              hipStream_t stream)
{
    const float* feats[5] = {
        (const float*)d_in[0], (const float*)d_in[1], (const float*)d_in[2],
        (const float*)d_in[3], (const float*)d_in[4]
    };
    const float* W_blocks = (const float*)d_in[25];
    const float* bn_gamma = (const float*)d_in[27];
    const float* bn_beta  = (const float*)d_in[28];
    const float* prelu_a  = (const float*)d_in[29];
    const float* attn_W1  = (const float*)d_in[30];
    const float* attn_b1  = (const float*)d_in[31];
    const float* attn_w2  = (const float*)d_in[32];
    float* out = (float*)d_out;

    // ---- d_out scratch (dead before combine writes): xbf | aggb | csrE ----
    unsigned* xbf  = (unsigned*)out;                    // 5,120,000 uints
    unsigned* aggb = (unsigned*)(out + 5120000);        // 5,120,000 uints
    int*      csrE = (int*)(out + 10240000);            // 8,960,000 ints (ends 19,200,000)

    // ---- workspace carve (4-byte slots) ----
    float* wsf = (float*)d_ws;
    unsigned short* wsvb = (unsigned short*)wsf;              // 71,680,000 bf16 = 35,840,000 slots
    unsigned short* wtbf = (unsigned short*)(wsf + 35840000); // 262,144 bf16 = 131,072 slots
    int* degs     = (int*)(wsf + 35971072);                   // 560,000
    int* rowStart = degs + 560000;                            // 560,000
    int* rowCnt   = rowStart + 560000;                        // 560,000
    int* histD    = rowCnt + 560000;                          // 2194 x 80 = 175,520
    int* histS    = histD + 175520;                           // 175,520
    int* colbaseD = histS + 175520;                           // 2,195
    int* totalsD  = colbaseD + 2195;                          // 2,194
    int* colbaseS = totalsD + 2194;                           // 2,195
    int* totalsS  = colbaseS + 2195;                          // 2,194
    int* epart    = totalsS + 2194;                           // 8,960,000
    unsigned char* spart = (unsigned char*)(epart + 8960000); // 8,960,000 bytes = 2,240,000 slots
    float* statsraw = (float*)(epart + 8960000 + 2240000);    // 2,560
    float* statsfin = statsraw + 2560;                        // 2,560
    float* Ssum     = statsfin + 2560;                        // 16
    size_t needed = ((size_t)((float*)(Ssum + 16) - wsf)) * 4;
    if (ws_size < needed) return;

    // tensors: T0 d0, T1 d1, T2 dis0, T3 dis4, T4 p1, T5 p2, T6 g2, T7 g3, T8 pw3, T9 pw4
    const int Mt[10]  = {40000, 40000, 40000, 40000, 80000, 80000, 80000, 80000, 40000, 40000};
    const int blk[10] = {0, 1, 0, 4, 1, 2, 2, 3, 3, 4};
    size_t offV[10];
    {
        size_t o = 0;
        for (int t = 0; t < 10; t++) { offV[t] = o; o += (size_t)Mt[t] * 128; }
    }
    unsigned short* Vb[10];
    for (int t = 0; t < 10; t++) Vb[t] = wsvb + offV[t];
    const size_t offT[5] = {0, 5120000, 10240000, 20480000, 30720000};

    // rel order: dd, ddi, dp, disdis, pp, pg, gg, gpw, pwpw, pwdis
    const int relFeat[10] = {0, 0, 0, 1, 2, 2, 3, 3, 4, 4};
    const int relSrc[10]  = {5, 7, 11, 9, 13, 15, 17, 19, 21, 23};
    const int relNs[10]   = {40000, 40000, 40000, 40000, 80000, 80000, 80000, 80000, 40000, 40000};
    const int relNd[10]   = {40000, 40000, 80000, 40000, 80000, 80000, 80000, 40000, 40000, 40000};
    const int relE[10]    = {640000, 640000, 640000, 640000, 1280000,
                             1280000, 1280000, 1280000, 640000, 640000};
    const int cumBlk[11]  = {0, 40, 80, 120, 160, 239, 318, 397, 476, 516, 556};
    // dst buckets 256-wide (per relNd)
    const int dstColBase[11] = {0, 157, 314, 627, 784, 1097, 1410, 1723, 1880, 2037, 2194};
    // src buckets 256-wide (per relNs)
    const int srcColBase[11] = {0, 157, 314, 471, 628, 941, 1254, 1567, 1880, 2037, 2194};
    const int degsBase[10]   = {0, 40000, 80000, 120000, 160000, 240000, 320000, 400000, 480000, 520000};
    const int cursorBase[10] = {0, 40000, 80000, 160000, 200000, 280000, 360000, 440000, 480000, 520000};

    struct GJob { int tid; int widx; int accum; int stats; };
    const int relNjob[10] = {2, 1, 1, 2, 2, 1, 2, 1, 2, 1};
    const GJob relJob[10][2] = {
        {{0,  0, 0, 1}, {1,  3, 0, 1}},  // dd      -> completes T0, T1
        {{2,  1, 0, 0}, {0,  0, 0, 0}},  // ddi
        {{4,  4, 0, 0}, {0,  0, 0, 0}},  // dp
        {{2,  2, 1, 1}, {3, 14, 0, 0}},  // disdis  -> completes T2
        {{4,  5, 1, 1}, {5,  6, 0, 1}},  // pp      -> completes T4, T5
        {{6,  7, 0, 0}, {0,  0, 0, 0}},  // pg
        {{6,  8, 1, 1}, {7,  9, 0, 1}},  // gg      -> completes T6, T7
        {{8, 10, 0, 0}, {0,  0, 0, 0}},  // gpw
        {{8, 11, 1, 1}, {9, 12, 0, 1}},  // pwpw    -> completes T8, T9
        {{3, 13, 1, 1}, {0,  0, 0, 0}},  // pwdis   -> completes T3
    };
    const int doneCnt[10] = {2, 0, 0, 1, 2, 0, 2, 0, 2, 1};
    const int doneT[10][2] = {{0,1},{0,0},{0,0},{2,0},{4,5},{0,0},{6,7},{0,0},{8,9},{3,0}};

    // ---- one-time conversions & zeroing ----
    wconv_t<<<16, 256, 0, stream>>>(W_blocks, attn_W1, wtbf);
    hipMemsetAsync(statsraw, 0, (2560 + 2560 + 16) * sizeof(float), stream);

    // ---- batched partitioned CSR build ----
    BuildArgs BA;
    ScanArgs  SAD, SAS;
    ScatArgs  CA;
    SortArgs  SO;
    DegArgs   DA;
    for (int r = 0; r < 10; r++) {
        BA.esrc[r] = (const int*)d_in[relSrc[r]];
        BA.edst[r] = (const int*)d_in[relSrc[r] + 1];
        BA.E[r] = relE[r];
        CA.esrc[r] = BA.esrc[r]; CA.edst[r] = BA.edst[r]; CA.E[r] = relE[r];
        SO.cursorBase[r] = cursorBase[r];
        SO.nd[r] = relNd[r];
        DA.degsBase[r] = degsBase[r];
        DA.ns[r] = relNs[r];
    }
    for (int i = 0; i < 11; i++) {
        BA.cumBlk[i] = cumBlk[i]; BA.dstColBase[i] = dstColBase[i]; BA.srcColBase[i] = srcColBase[i];
        SAD.colBase[i] = dstColBase[i]; SAD.cumBlk[i] = cumBlk[i];
        SAS.colBase[i] = srcColBase[i]; SAS.cumBlk[i] = cumBlk[i];
        CA.cumBlk[i] = cumBlk[i]; CA.dstColBase[i] = dstColBase[i]; CA.srcColBase[i] = srcColBase[i];
        SO.dstColBase[i] = dstColBase[i];
        DA.colBase[i] = srcColBase[i];
    }
    BA.histD = histD; BA.histS = histS;
    SAD.hist = histD; SAD.totals = totalsD;
    SAS.hist = histS; SAS.totals = totalsS;
    CA.histD = histD; CA.colbaseD = colbaseD;
    CA.histS = histS; CA.colbaseS = colbaseS;
    CA.epart = epart; CA.spart = spart;
    SO.epart = epart; SO.colbase = colbaseD;
    SO.csrE = csrE; SO.rowStart = rowStart; SO.rowCnt = rowCnt;
    DA.spart = spart; DA.colbase = colbaseS; DA.degs = degs;

    part_count<<<556, 256, 0, stream>>>(BA);
    col_scan<<<2194, 256, 0, stream>>>(SAD);
    col_scan<<<2194, 256, 0, stream>>>(SAS);
    base_scan<<<1, 256, 0, stream>>>(totalsD, colbaseD, 2194);
    base_scan<<<1, 256, 0, stream>>>(totalsS, colbaseS, 2194);
    scatter_all<<<556, 256, 0, stream>>>(CA);
    bucket_sort<<<2194, 256, 0, stream>>>(SO);
    deg_count<<<2194, 256, 0, stream>>>(DA);

    // ---- per-rel scaled-xconv + gather + GEMM + L3-hot attention ----
    for (int r = 0; r < 10; r++) {
        xconv_scaled<<<(relNs[r] + 3) / 4, 256, 0, stream>>>(
            feats[relFeat[r]], degs + degsBase[r], xbf, relNs[r]);
        gather_bf16<<<relNd[r] / 4, 256, 0, stream>>>(
            xbf, rowStart + cursorBase[r], rowCnt + cursorBase[r],
            csrE, epart, colbaseD, dstColBase[r], aggb, relNd[r]);
        if (relNjob[r] == 2) {
            const GJob& G0 = relJob[r][0];
            const GJob& G1 = relJob[r][1];
            gemm_mfma2<<<relNd[r] / 64, 256, 0, stream>>>(
                (const unsigned short*)aggb,
                wtbf + (size_t)G0.widx * 16384, wtbf + (size_t)G1.widx * 16384,
                Vb[G0.tid], Vb[G1.tid], G0.accum, G1.accum, G0.stats, G1.stats,
                statsraw + (size_t)G0.tid * 256, statsraw + (size_t)G1.tid * 256);
        } else {
            const GJob& G = relJob[r][0];
            gemm_mfma<<<relNd[r] / 64, 256, 0, stream>>>(
                (const unsigned short*)aggb, wtbf + (size_t)G.widx * 16384,
                Vb[G.tid], G.accum, G.stats, statsraw + (size_t)G.tid * 256);
        }
        for (int k = 0; k < doneCnt[r]; k++) {
            int t = doneT[r][k];
            attn_t<<<Mt[t] / 64, 256, 0, stream>>>(
                Vb[t], statsraw + (size_t)t * 256, 1.0f / Mt[t],
                bn_gamma + blk[t] * 128, bn_beta + blk[t] * 128, prelu_a + blk[t],
                wtbf + (size_t)15 * 16384, attn_b1, attn_w2, Ssum + t);
        }
    }

    FinArgs fa;
    for (int t = 0; t < 10; t++) fa.Ms[t] = Mt[t];
    bn_finalize<<<10, 128, 0, stream>>>(statsraw, statsfin, fa);

    CombArgs CD;
    CD.stats = statsfin; CD.gam = bn_gamma; CD.bet = bn_beta; CD.pa = prelu_a; CD.S = Ssum;
    CD.cum[0] = 0;
    for (int p = 0; p < 5; p++) {
        CD.outp[p] = out + offT[p];
        CD.va[p] = Vb[p * 2];
        CD.vb[p] = Vb[p * 2 + 1];
        CD.ta[p] = p * 2; CD.tb[p] = p * 2 + 1;
        CD.blka[p] = blk[p * 2]; CD.blkb[p] = blk[p * 2 + 1];
        CD.invM[p] = 1.0f / Mt[p * 2];
        CD.cum[p + 1] = CD.cum[p] + Mt[p * 2] / 2;
    }
    combine_all<<<CD.cum[5], 256, 0, stream>>>(CD);
}

// Round 20
// 1467.634 us; speedup vs baseline: 1.7171x; 1.0255x over previous
//
#include <hip/hip_runtime.h>
#include <hip/hip_bf16.h>

#define D128 128
#define STAGE 12288

typedef __attribute__((ext_vector_type(8))) short bf16x8;
typedef __attribute__((ext_vector_type(4))) float f32x4;

__device__ inline unsigned short f2bf(float f) {
    unsigned u = __float_as_uint(f);
    u = u + 0x7fffu + ((u >> 16) & 1u);
    return (unsigned short)(u >> 16);
}
__device__ inline float bf2f(unsigned short h) {
    return __uint_as_float(((unsigned)h) << 16);
}
__device__ inline float fast_tanh(float x) {
    float e = __expf(2.f * x);
    return 1.f - 2.f * __builtin_amdgcn_rcpf(e + 1.f);
}

// stage a 128x128 bf16 W into LDS with 16B-slot XOR swizzle (slot ^= row&7)
__device__ __forceinline__ void stage_w(const unsigned short* __restrict__ Wt,
                                        unsigned short* lw, int t)
{
    const uint4* srcW = (const uint4*)Wt;
    uint4* dstW = (uint4*)lw;
    for (int i = t; i < 2048; i += 256) {
        int row = i >> 4, sl = i & 15;
        dstW[row * 16 + (sl ^ (row & 7))] = srcW[i];
    }
}
__device__ __forceinline__ bf16x8 read_w(const unsigned short* lw, int row, int kt, int lq)
{
    int slot = (kt * 4 + lq) ^ (row & 7);
    return *(const bf16x8*)(lw + row * 128 + slot * 8);
}

// wave-parallel exclusive scan of arr[0..n) into ofs[0..n], one 64-lane wave
__device__ __forceinline__ void wave_scan(const int* arr, int* ofs, int n, int lane)
{
    int k = (n + 63) >> 6;
    int base = lane * k;
    int sum = 0;
    for (int i = 0; i < k; i++) { int idx = base + i; if (idx < n) sum += arr[idx]; }
    int pre = sum;
    for (int off = 1; off < 64; off <<= 1) {
        int u = __shfl(pre, (lane - off) & 63);
        if (lane >= off) pre += u;
    }
    int run = pre - sum;
    for (int i = 0; i < k; i++) { int idx = base + i; if (idx < n) { ofs[idx] = run; run += arr[idx]; } }
    if (lane == 63) ofs[n] = run;
}

// ---------------- per-rel pre-scaled bf16 feature conversion ----------------
__global__ __launch_bounds__(256) void xconv_scaled(
    const float* __restrict__ in, const int* __restrict__ degs,
    unsigned* __restrict__ out, int nrows)
{
    int t = threadIdx.x;
    int lane = t & 63, rr = t >> 6;
    int row = blockIdx.x * 4 + rr;
    if (row >= nrows) return;
    float sc = rsqrtf((float)max(degs[row], 1));
    float2 v = ((const float2*)(in + (size_t)row * 128))[lane];
    out[(size_t)row * 64 + lane] =
        (unsigned)f2bf(v.x * sc) | ((unsigned)f2bf(v.y * sc) << 16);
}

// ---------------- weight transpose + convert: Wt[n][k] = W[k][n] ----------------
__global__ void wconv_t(const float* __restrict__ W_blocks, const float* __restrict__ W1,
                        unsigned short* __restrict__ wt)
{
    int m = blockIdx.x;  // 0..15
    const float* src = (m < 15) ? (W_blocks + (size_t)m * 16384) : W1;
    unsigned short* dst = wt + (size_t)m * 16384;
    for (int i = threadIdx.x; i < 16384; i += 256) {
        int n = i >> 7, k = i & 127;
        dst[i] = f2bf(src[k * 128 + n]);
    }
}

// ================= partitioned CSR build (16384 edges/block; 256-wide buckets) ==========
struct BuildArgs {
    const int* esrc[10]; const int* edst[10];
    int* histD; int* histS;
    int cumBlk[11]; int dstColBase[11]; int srcColBase[11]; int E[10];
};

__global__ __launch_bounds__(256) void part_count(BuildArgs A)
{
    __shared__ int hd[320], hs[320];
    int blk = blockIdx.x, t = threadIdx.x;
    int r = 0;
    while (r < 9 && blk >= A.cumBlk[r + 1]) r++;
    int blkInRel = blk - A.cumBlk[r];
    int nbD = A.dstColBase[r + 1] - A.dstColBase[r];
    int nbS = A.srcColBase[r + 1] - A.srcColBase[r];
    for (int i = t; i < nbD; i += 256) hd[i] = 0;
    for (int i = t; i < nbS; i += 256) hs[i] = 0;
    __syncthreads();
    int e0 = blkInRel * 16384;
    const int* sp = A.esrc[r];
    const int* dp = A.edst[r];
    int E = A.E[r];
#pragma unroll 4
    for (int j = 0; j < 64; j++) {
        int e = e0 + j * 256 + t;
        if (e < E) {
            atomicAdd(&hd[dp[e] >> 8], 1);
            atomicAdd(&hs[sp[e] >> 8], 1);
        }
    }
    __syncthreads();
    int cd = A.dstColBase[r], cs = A.srcColBase[r];
    for (int i = t; i < nbD; i += 256)
        A.histD[(size_t)(cd + i) * 80 + blkInRel] = hd[i];
    for (int i = t; i < nbS; i += 256)
        A.histS[(size_t)(cs + i) * 80 + blkInRel] = hs[i];
}

struct ScanArgs { int* hist; int* totals; int colBase[11]; int cumBlk[11]; };

__global__ __launch_bounds__(256) void col_scan(ScanArgs A)
{
    __shared__ int v[80];
    int col = blockIdx.x, t = threadIdx.x;
    int r = 0;
    while (r < 9 && col >= A.colBase[r + 1]) r++;
    int nblk = A.cumBlk[r + 1] - A.cumBlk[r];
    for (int i = t; i < nblk; i += 256) v[i] = A.hist[(size_t)col * 80 + i];
    __syncthreads();
    if (t == 0) {
        int run = 0;
        for (int i = 0; i < nblk; i++) { int c = v[i]; v[i] = run; run += c; }
        A.totals[col] = run;
    }
    __syncthreads();
    for (int i = t; i < nblk; i += 256) A.hist[(size_t)col * 80 + i] = v[i];
}

__global__ __launch_bounds__(256) void base_scan(const int* __restrict__ totals,
                                                 int* __restrict__ colbase, int n)
{
    __shared__ int v[2200];
    int t = threadIdx.x;
    for (int i = t; i < n; i += 256) v[i] = totals[i];
    __syncthreads();
    if (t == 0) {
        int run = 0;
        for (int i = 0; i < n; i++) { int c = v[i]; v[i] = run; run += c; }
        v[n] = run;
    }
    __syncthreads();
    for (int i = t; i <= n; i += 256) colbase[i] = v[i];
}

// fused scatter with chunked LDS staging: bucket-sorted flushes, contiguous cursors
struct ScatArgs {
    const int* esrc[10]; const int* edst[10];
    const int* histD; const int* colbaseD;
    const int* histS; const int* colbaseS;
    int* epart; unsigned char* spart;
    int cumBlk[11]; int dstColBase[11]; int srcColBase[11]; int E[10];
};

__global__ __launch_bounds__(256) void scatter_all(ScatArgs A)
{
    __shared__ int stageE[4096];
    __shared__ unsigned short bidE[4096];
    __shared__ unsigned short bidS[4096];
    __shared__ unsigned char stageS[4096];
    __shared__ int gbaseD[320], gcurD[320], lhistD[320], lofsD[321];
    __shared__ int gbaseS[320], gcurS[320], lhistS[320], lofsS[321];

    int blk = blockIdx.x, t = threadIdx.x;
    int r = 0;
    while (r < 9 && blk >= A.cumBlk[r + 1]) r++;
    int blkInRel = blk - A.cumBlk[r];
    int cd = A.dstColBase[r], cs = A.srcColBase[r];
    int nbD = A.dstColBase[r + 1] - cd;
    int nbS = A.srcColBase[r + 1] - cs;
    for (int i = t; i < nbD; i += 256) {
        gbaseD[i] = A.colbaseD[cd + i] + A.histD[(size_t)(cd + i) * 80 + blkInRel];
        gcurD[i] = 0;
    }
    for (int i = t; i < nbS; i += 256) {
        gbaseS[i] = A.colbaseS[cs + i] + A.histS[(size_t)(cs + i) * 80 + blkInRel];
        gcurS[i] = 0;
    }
    const int* sp = A.esrc[r];
    const int* dp = A.edst[r];
    int E = A.E[r];
    int blkbase = blkInRel * 16384;

    for (int c = 0; c < 4; c++) {
        int e0 = blkbase + c * 4096;
        int sv[16], dv[16];
#pragma unroll
        for (int j = 0; j < 16; j++) {
            int e = e0 + j * 256 + t;
            sv[j] = (e < E) ? sp[e] : -1;
            dv[j] = (e < E) ? dp[e] : 0;
        }
        for (int i = t; i < nbD; i += 256) lhistD[i] = 0;
        for (int i = t; i < nbS; i += 256) lhistS[i] = 0;
        __syncthreads();
#pragma unroll
        for (int j = 0; j < 16; j++) {
            if (sv[j] >= 0) {
                atomicAdd(&lhistD[dv[j] >> 8], 1);
                atomicAdd(&lhistS[sv[j] >> 8], 1);
            }
        }
        __syncthreads();
        if (t < 64) wave_scan(lhistD, lofsD, nbD, t);
        else if (t < 128) wave_scan(lhistS, lofsS, nbS, t - 64);
        __syncthreads();
        for (int i = t; i < nbD; i += 256) lhistD[i] = 0;
        for (int i = t; i < nbS; i += 256) lhistS[i] = 0;
        __syncthreads();
#pragma unroll
        for (int j = 0; j < 16; j++) {
            if (sv[j] >= 0) {
                int bd = dv[j] >> 8;
                int p = atomicAdd(&lhistD[bd], 1);
                int ix = lofsD[bd] + p;
                stageE[ix] = (sv[j] & 0x1FFFF) | ((dv[j] & 255) << 17);
                bidE[ix] = (unsigned short)bd;
                int bs = sv[j] >> 8;
                int q = atomicAdd(&lhistS[bs], 1);
                int iy = lofsS[bs] + q;
                stageS[iy] = (unsigned char)(sv[j] & 255);
                bidS[iy] = (unsigned short)bs;
            }
        }
        __syncthreads();
        int cntv = lofsD[nbD];
        for (int i = t; i < cntv; i += 256) {
            int b = bidE[i];
            A.epart[gbaseD[b] + gcurD[b] + i - lofsD[b]] = stageE[i];
        }
        for (int i = t; i < cntv; i += 256) {
            int b = bidS[i];
            A.spart[(size_t)gbaseS[b] + gcurS[b] + i - lofsS[b]] = stageS[i];
        }
        __syncthreads();
        for (int i = t; i < nbD; i += 256) gcurD[i] += lofsD[i + 1] - lofsD[i];
        for (int i = t; i < nbS; i += 256) gcurS[i] += lofsS[i + 1] - lofsS[i];
        __syncthreads();
    }
}

// per-256-src-bucket degree count
struct DegArgs {
    const unsigned char* spart; const int* colbase;
    int* degs;
    int colBase[11]; int degsBase[10]; int ns[10];
};

__global__ __launch_bounds__(256) void deg_count(DegArgs A)
{
    __shared__ int lc[256];
    int col = blockIdx.x, t = threadIdx.x;
    int r = 0;
    while (r < 9 && col >= A.colBase[r + 1]) r++;
    int b = col - A.colBase[r];
    lc[t] = 0;
    __syncthreads();
    int start = A.colbase[col], end = A.colbase[col + 1];
    for (int i = start + t; i < end; i += 256)
        atomicAdd(&lc[A.spart[i]], 1);
    __syncthreads();
    int s = b * 256 + t;
    if (s < A.ns[r]) A.degs[A.degsBase[r] + s] = lc[t];
}

// ---------------- per-bucket LDS counting sort -> packed CSR (coalesced writes) -------
struct SortArgs {
    const int* epart; const int* colbase;
    int* csrE; int* rowStart; int* rowCnt;
    int dstColBase[11]; int cursorBase[10]; int nd[10];
};

__global__ __launch_bounds__(256) void bucket_sort(SortArgs A)
{
    __shared__ int stage[STAGE];
    __shared__ int lhist[256], lofs[257];
    int col = blockIdx.x, t = threadIdx.x;
    int r = 0;
    while (r < 9 && col >= A.dstColBase[r + 1]) r++;
    int b = col - A.dstColBase[r];
    int start = A.colbase[col], end = A.colbase[col + 1];
    int total = end - start;
    int main_ = min(total, STAGE);

    lhist[t] = 0;
    __syncthreads();
    for (int i = t; i < main_; i += 256)
        atomicAdd(&lhist[(A.epart[start + i] >> 17) & 255], 1);
    __syncthreads();
    if (t < 64) wave_scan(lhist, lofs, 256, t);
    __syncthreads();
    lhist[t] = 0;
    __syncthreads();
    for (int i = t; i < main_; i += 256) {
        int v = A.epart[start + i];
        int b8 = (v >> 17) & 255;
        int p = atomicAdd(&lhist[b8], 1);
        stage[lofs[b8] + p] = v & 0x1FFFF;
    }
    __syncthreads();
    for (int i = t; i < main_; i += 256)
        A.csrE[start + i] = stage[i];
    int d = b * 256 + t;
    if (d < A.nd[r]) {
        A.rowStart[A.cursorBase[r] + d] = start + lofs[t];
        A.rowCnt[A.cursorBase[r] + d] = lofs[t + 1] - lofs[t];
    }
}

// ---------------- bf16 CSR gather over packed rows (X pre-scaled) ----------------
__global__ __launch_bounds__(256) void gather_bf16(
    const unsigned* __restrict__ Xb,
    const int* __restrict__ rowStart, const int* __restrict__ rowCnt,
    const int* __restrict__ csrE, const int* __restrict__ epart,
    const int* __restrict__ colbase, int colBase0,
    unsigned* __restrict__ aggb, int nd)
{
    int t = threadIdx.x;
    int lane = t & 63, r = t >> 6;
    int d = blockIdx.x * 4 + r;
    if (d >= nd) return;
    int st = rowStart[d];
    int cnt = rowCnt[d];
    const int* eb = csrE + st;
    float a0 = 0.f, a1 = 0.f;
    int i = 0;
    for (; i + 4 <= cnt; i += 4) {
        int s0 = eb[i], s1 = eb[i + 1], s2 = eb[i + 2], s3 = eb[i + 3];
        unsigned x0 = Xb[(size_t)s0 * 64 + lane];
        unsigned x1 = Xb[(size_t)s1 * 64 + lane];
        unsigned x2 = Xb[(size_t)s2 * 64 + lane];
        unsigned x3 = Xb[(size_t)s3 * 64 + lane];
        a0 += bf2f((unsigned short)(x0 & 0xffff)) + bf2f((unsigned short)(x1 & 0xffff))
            + bf2f((unsigned short)(x2 & 0xffff)) + bf2f((unsigned short)(x3 & 0xffff));
        a1 += bf2f((unsigned short)(x0 >> 16)) + bf2f((unsigned short)(x1 >> 16))
            + bf2f((unsigned short)(x2 >> 16)) + bf2f((unsigned short)(x3 >> 16));
    }
    for (; i < cnt; i++) {
        int s0 = eb[i];
        unsigned x0 = Xb[(size_t)s0 * 64 + lane];
        a0 += bf2f((unsigned short)(x0 & 0xffff));
        a1 += bf2f((unsigned short)(x0 >> 16));
    }
    // astronomically-rare unsorted tail (bucket exceeded STAGE): scan packed epart
    int col = colBase0 + (d >> 8);
    int s0c = colbase[col], e0c = colbase[col + 1];
    int tot = cnt;
    if (e0c - s0c > STAGE) {
        for (int j = s0c + STAGE; j < e0c; j++) {
            int v = epart[j];
            if (((v >> 17) & 255) == (d & 255)) {
                int s0 = v & 0x1FFFF;
                unsigned x0 = Xb[(size_t)s0 * 64 + lane];
                a0 += bf2f((unsigned short)(x0 & 0xffff));
                a1 += bf2f((unsigned short)(x0 >> 16));
                tot++;
            }
        }
    }
    float sc = rsqrtf((float)max(tot, 1));
    a0 *= sc; a1 *= sc;
    aggb[(size_t)d * 64 + lane] = (unsigned)f2bf(a0) | ((unsigned)f2bf(a1) << 16);
}

// ---------------- GEMM epilogue: bf16 store + fused BN stats ----------------
__device__ __forceinline__ void epi_store(
    f32x4* acc, unsigned short* __restrict__ Vb, int accum, int do_stats,
    float* ssum, float* ssq, int row0, int lr, int lq)
{
#pragma unroll
    for (int n = 0; n < 8; n++) {
        int col = n * 16 + lr;
        float s_ = 0.f, q_ = 0.f;
#pragma unroll
        for (int reg = 0; reg < 4; reg++) {
            int row = row0 + lq * 4 + reg;
            float v = acc[n][reg];
            unsigned short* vp = &Vb[(size_t)row * D128 + col];
            if (accum) v += bf2f(*vp);
            *vp = f2bf(v);
            s_ += v; q_ += v * v;
        }
        if (do_stats) {
            s_ += __shfl_xor(s_, 16); s_ += __shfl_xor(s_, 32);
            q_ += __shfl_xor(q_, 16); q_ += __shfl_xor(q_, 32);
            if (lq == 0) {
                atomicAdd(&ssum[col], s_);
                atomicAdd(&ssq[col], q_);
            }
        }
    }
}

// ---------------- single-output MFMA GEMM (W staged in LDS) ----------------
__global__ __launch_bounds__(256) void gemm_mfma(
    const unsigned short* __restrict__ A, const unsigned short* __restrict__ Wt,
    unsigned short* __restrict__ Vb, int accum, int do_stats, float* __restrict__ statsraw)
{
    __shared__ unsigned short lw[16384];
    __shared__ float ssum[128], ssq[128];
    int t = threadIdx.x;
    int wave = t >> 6, lane = t & 63;
    int lr = lane & 15, lq = lane >> 4;
    int row0 = blockIdx.x * 64 + wave * 16;

    if (t < 128) { ssum[t] = 0.f; ssq[t] = 0.f; }
    stage_w(Wt, lw, t);
    __syncthreads();

    f32x4 acc[8];
#pragma unroll
    for (int n = 0; n < 8; n++) acc[n] = (f32x4)(0.f);

    const unsigned short* arow = A + (size_t)(row0 + lr) * 128 + lq * 8;
#pragma unroll
    for (int kt = 0; kt < 4; kt++) {
        bf16x8 af = *(const bf16x8*)(arow + kt * 32);
#pragma unroll
        for (int n = 0; n < 8; n++) {
            bf16x8 bfr = read_w(lw, n * 16 + lr, kt, lq);
            acc[n] = __builtin_amdgcn_mfma_f32_16x16x32_bf16(af, bfr, acc[n], 0, 0, 0);
        }
    }
    epi_store(acc, Vb, accum, do_stats, ssum, ssq, row0, lr, lq);
    if (do_stats) {
        __syncthreads();
        if (t < 128) atomicAdd(&statsraw[t], ssum[t]);
        else atomicAdd(&statsraw[t], ssq[t - 128]);
    }
}

// ---------------- dual-output MFMA GEMM (A loaded once, both W in LDS) ----------------
__global__ __launch_bounds__(256) void gemm_mfma2(
    const unsigned short* __restrict__ A,
    const unsigned short* __restrict__ Wt0, const unsigned short* __restrict__ Wt1,
    unsigned short* __restrict__ V0b, unsigned short* __restrict__ V1b,
    int acc0f, int acc1f, int st0, int st1,
    float* __restrict__ sr0, float* __restrict__ sr1)
{
    __shared__ unsigned short lw0[16384], lw1[16384];
    __shared__ float ssum0[128], ssq0[128], ssum1[128], ssq1[128];
    int t = threadIdx.x;
    int wave = t >> 6, lane = t & 63;
    int lr = lane & 15, lq = lane >> 4;
    int row0 = blockIdx.x * 64 + wave * 16;

    if (t < 128) { ssum0[t] = 0.f; ssq0[t] = 0.f; ssum1[t] = 0.f; ssq1[t] = 0.f; }
    stage_w(Wt0, lw0, t);
    stage_w(Wt1, lw1, t);
    __syncthreads();

    f32x4 acc0[8], acc1[8];
#pragma unroll
    for (int n = 0; n < 8; n++) { acc0[n] = (f32x4)(0.f); acc1[n] = (f32x4)(0.f); }

    const unsigned short* arow = A + (size_t)(row0 + lr) * 128 + lq * 8;
#pragma unroll
    for (int kt = 0; kt < 4; kt++) {
        bf16x8 af = *(const bf16x8*)(arow + kt * 32);
#pragma unroll
        for (int n = 0; n < 8; n++) {
            int row = n * 16 + lr;
            bf16x8 b0 = read_w(lw0, row, kt, lq);
            bf16x8 b1 = read_w(lw1, row, kt, lq);
            acc0[n] = __builtin_amdgcn_mfma_f32_16x16x32_bf16(af, b0, acc0[n], 0, 0, 0);
            acc1[n] = __builtin_amdgcn_mfma_f32_16x16x32_bf16(af, b1, acc1[n], 0, 0, 0);
        }
    }
    epi_store(acc0, V0b, acc0f, st0, ssum0, ssq0, row0, lr, lq);
    epi_store(acc1, V1b, acc1f, st1, ssum1, ssq1, row0, lr, lq);
    __syncthreads();
    if (st0) {
        if (t < 128) atomicAdd(&sr0[t], ssum0[t]);
        else atomicAdd(&sr0[t], ssq0[t - 128]);
    }
    if (st1) {
        if (t < 128) atomicAdd(&sr1[t], ssum1[t]);
        else atomicAdd(&sr1[t], ssq1[t - 128]);
    }
}

struct FinArgs { int Ms[10]; };

__global__ void bn_finalize(const float* __restrict__ raw, float* __restrict__ fin, FinArgs fa)
{
    int tt = blockIdx.x;
    int c = threadIdx.x;
    float m = (float)fa.Ms[tt];
    float s = raw[tt * 256 + c], sq = raw[tt * 256 + 128 + c];
    float mu = s / m;
    float var = fmaxf(sq / m - mu * mu, 0.f);
    fin[tt * 256 + c] = mu;
    fin[tt * 256 + 128 + c] = rsqrtf(var + 1e-5f);
}

// ---------------- per-tensor attention score (L3-hot, inline BN stats) ----------------
__global__ __launch_bounds__(256) void attn_t(
    const unsigned short* __restrict__ Vb, const float* __restrict__ raw, float Minv,
    const float* __restrict__ gam, const float* __restrict__ bet,
    const float* __restrict__ pa,
    const unsigned short* __restrict__ W1t, const float* __restrict__ b1,
    const float* __restrict__ w2, float* __restrict__ Sout)
{
    __shared__ float st[256];
    __shared__ float red[4];
    int t = threadIdx.x;
    if (t < 128) {
        float mu = raw[t] * Minv;
        float var = fmaxf(raw[128 + t] * Minv - mu * mu, 0.f);
        st[t] = mu;
        st[128 + t] = rsqrtf(var + 1e-5f);
    }
    __syncthreads();

    int wave = t >> 6, lane = t & 63;
    int lr = lane & 15, lq = lane >> 4;
    int row0 = blockIdx.x * 64 + wave * 16;
    float a = *pa;

    f32x4 acc[8];
#pragma unroll
    for (int n = 0; n < 8; n++) acc[n] = (f32x4)(0.f);

    const unsigned short* vrow = Vb + (size_t)(row0 + lr) * D128;
#pragma unroll
    for (int kt = 0; kt < 4; kt++) {
        int k0 = kt * 32 + lq * 8;
        bf16x8 vv = *(const bf16x8*)(vrow + k0);
        bf16x8 af;
#pragma unroll
        for (int jj = 0; jj < 8; jj++) {
            int cc = k0 + jj;
            float y = bf2f((unsigned short)vv[jj]);
            float yy = gam[cc] * (y - st[cc]) * st[128 + cc] + bet[cc];
            yy = yy >= 0.f ? yy : a * yy;
            af[jj] = (short)f2bf(yy);
        }
#pragma unroll
        for (int n = 0; n < 8; n++) {
            bf16x8 bfr = *(const bf16x8*)(W1t + (size_t)(n * 16 + lr) * 128 + k0);
            acc[n] = __builtin_amdgcn_mfma_f32_16x16x32_bf16(af, bfr, acc[n], 0, 0, 0);
        }
    }

    float thr = 0.f;
#pragma unroll
    for (int n = 0; n < 8; n++) {
        int col = n * 16 + lr;
        float bc = b1[col], wc = w2[col];
#pragma unroll
        for (int reg = 0; reg < 4; reg++)
            thr += fast_tanh(acc[n][reg] + bc) * wc;
    }
#pragma unroll
    for (int off = 1; off < 64; off <<= 1)
        thr += __shfl_xor(thr, off);
    if (lane == 0) red[wave] = thr;
    __syncthreads();
    if (t == 0) atomicAdd(Sout, red[0] + red[1] + red[2] + red[3]);
}

// ---------------- all-pair combine (vectorized: 8 elements/thread) ----------------
struct CombArgs {
    float* outp[5]; const unsigned short* va[5]; const unsigned short* vb[5];
    const float* stats; const float* gam; const float* bet; const float* pa; const float* S;
    int ta[5]; int tb[5]; int blka[5]; int blkb[5]; float invM[5]; int cum[6];
};

__global__ __launch_bounds__(256) void combine_all(CombArgs D)
{
    int b = blockIdx.x, t = threadIdx.x;
    int p = 0;
    while (p < 4 && b >= D.cum[p + 1]) p++;
    size_t idx8 = ((size_t)(b - D.cum[p]) * 256 + t) * 8;   // 8 consecutive elements, one row
    int c0 = (int)(idx8 & 127);
    float s0 = D.S[2 * p] * D.invM[p], s1 = D.S[2 * p + 1] * D.invM[p];
    float mx = fmaxf(s0, s1);
    float e0 = __expf(s0 - mx), e1 = __expf(s1 - mx);
    float inv = 1.f / (e0 + e1);
    float b0 = e0 * inv, b1w = e1 * inv;
    const float* sta = D.stats + D.ta[p] * 256;
    const float* stb = D.stats + D.tb[p] * 256;
    const float* ga = D.gam + D.blka[p] * 128;
    const float* ba = D.bet + D.blka[p] * 128;
    const float* gb = D.gam + D.blkb[p] * 128;
    const float* bb = D.bet + D.blkb[p] * 128;
    float aa = D.pa[D.blka[p]], ab = D.pa[D.blkb[p]];
    bf16x8 va8 = *(const bf16x8*)(D.va[p] + idx8);
    bf16x8 vb8 = *(const bf16x8*)(D.vb[p] + idx8);
    float o[8];
#pragma unroll
    for (int j = 0; j < 8; j++) {
        int c = c0 + j;
        float va = bf2f((unsigned short)va8[j]);
        float vb = bf2f((unsigned short)vb8[j]);
        float ya = ga[c] * (va - sta[c]) * sta[128 + c] + ba[c];
        ya = ya >= 0.f ? ya : aa * ya;
        float yb = gb[c] * (vb - stb[c]) * stb[128 + c] + bb[c];
        yb = yb >= 0.f ? yb : ab * yb;
        o[j] = b0 * ya + b1w * yb;
    }
    float* op = D.outp[p] + idx8;
    *(float4*)op = make_float4(o[0], o[1], o[2], o[3]);
    *(float4*)(op + 4) = make_float4(o[4], o[5], o[6], o[7]);
}

// ---------------- host orchestration ----------------
extern "C" void kernel_launch(void* const* d_in, const int* in_sizes, int n_in,
                              void* d_out, int out_size, void* d_ws, size_t ws_size,
                              hipStream_t stream)
{
    const float* feats[5] = {
        (const float*)d_in[0], (const float*)d_in[1], (const float*)d_in[2],
        (const float*)d_in[3], (const float*)d_in[4]
    };
    const float* W_blocks = (const float*)d_in[25];
    const float* bn_gamma = (const float*)d_in[27];
    const float* bn_beta  = (const float*)d_in[28];
    const float* prelu_a  = (const float*)d_in[29];
    const float* attn_W1  = (const float*)d_in[30];
    const float* attn_b1  = (const float*)d_in[31];
    const float* attn_w2  = (const float*)d_in[32];
    float* out = (float*)d_out;

    // ---- d_out scratch (dead before combine writes): xbf | aggb | csrE ----
    unsigned* xbf  = (unsigned*)out;                    // 5,120,000 uints
    unsigned* aggb = (unsigned*)(out + 5120000);        // 5,120,000 uints
    int*      csrE = (int*)(out + 10240000);            // 8,960,000 ints (ends 19,200,000)

    // ---- workspace carve (4-byte slots) ----
    float* wsf = (float*)d_ws;
    unsigned short* wsvb = (unsigned short*)wsf;              // 71,680,000 bf16 = 35,840,000 slots
    unsigned short* wtbf = (unsigned short*)(wsf + 35840000); // 262,144 bf16 = 131,072 slots
    int* degs     = (int*)(wsf + 35971072);                   // 560,000
    int* rowStart = degs + 560000;                            // 560,000
    int* rowCnt   = rowStart + 560000;                        // 560,000
    int* histD    = rowCnt + 560000;                          // 2194 x 80 = 175,520
    int* histS    = histD + 175520;                           // 175,520
    int* colbaseD = histS + 175520;                           // 2,195
    int* totalsD  = colbaseD + 2195;                          // 2,194
    int* colbaseS = totalsD + 2194;                           // 2,195
    int* totalsS  = colbaseS + 2195;                          // 2,194
    int* epart    = totalsS + 2194;                           // 8,960,000
    unsigned char* spart = (unsigned char*)(epart + 8960000); // 8,960,000 bytes = 2,240,000 slots
    float* statsraw = (float*)(epart + 8960000 + 2240000);    // 2,560
    float* statsfin = statsraw + 2560;                        // 2,560
    float* Ssum     = statsfin + 2560;                        // 16
    size_t needed = ((size_t)((float*)(Ssum + 16) - wsf)) * 4;
    if (ws_size < needed) return;

    // tensors: T0 d0, T1 d1, T2 dis0, T3 dis4, T4 p1, T5 p2, T6 g2, T7 g3, T8 pw3, T9 pw4
    const int Mt[10]  = {40000, 40000, 40000, 40000, 80000, 80000, 80000, 80000, 40000, 40000};
    const int blk[10] = {0, 1, 0, 4, 1, 2, 2, 3, 3, 4};
    size_t offV[10];
    {
        size_t o = 0;
        for (int t = 0; t < 10; t++) { offV[t] = o; o += (size_t)Mt[t] * 128; }
    }
    unsigned short* Vb[10];
    for (int t = 0; t < 10; t++) Vb[t] = wsvb + offV[t];
    const size_t offT[5] = {0, 5120000, 10240000, 20480000, 30720000};

    // rel order: dd, ddi, dp, disdis, pp, pg, gg, gpw, pwpw, pwdis
    const int relFeat[10] = {0, 0, 0, 1, 2, 2, 3, 3, 4, 4};
    const int relSrc[10]  = {5, 7, 11, 9, 13, 15, 17, 19, 21, 23};
    const int relNs[10]   = {40000, 40000, 40000, 40000, 80000, 80000, 80000, 80000, 40000, 40000};
    const int relNd[10]   = {40000, 40000, 80000, 40000, 80000, 80000, 80000, 40000, 40000, 40000};
    const int relE[10]    = {640000, 640000, 640000, 640000, 1280000,
                             1280000, 1280000, 1280000, 640000, 640000};
    const int cumBlk[11]  = {0, 40, 80, 120, 160, 239, 318, 397, 476, 516, 556};
    const int dstColBase[11] = {0, 157, 314, 627, 784, 1097, 1410, 1723, 1880, 2037, 2194};
    const int srcColBase[11] = {0, 157, 314, 471, 628, 941, 1254, 1567, 1880, 2037, 2194};
    const int degsBase[10]   = {0, 40000, 80000, 120000, 160000, 240000, 320000, 400000, 480000, 520000};
    const int cursorBase[10] = {0, 40000, 80000, 160000, 200000, 280000, 360000, 440000, 480000, 520000};

    struct GJob { int tid; int widx; int accum; int stats; };
    const int relNjob[10] = {2, 1, 1, 2, 2, 1, 2, 1, 2, 1};
    const GJob relJob[10][2] = {
        {{0,  0, 0, 1}, {1,  3, 0, 1}},  // dd      -> completes T0, T1
        {{2,  1, 0, 0}, {0,  0, 0, 0}},  // ddi
        {{4,  4, 0, 0}, {0,  0, 0, 0}},  // dp
        {{2,  2, 1, 1}, {3, 14, 0, 0}},  // disdis  -> completes T2
        {{4,  5, 1, 1}, {5,  6, 0, 1}},  // pp      -> completes T4, T5
        {{6,  7, 0, 0}, {0,  0, 0, 0}},  // pg
        {{6,  8, 1, 1}, {7,  9, 0, 1}},  // gg      -> completes T6, T7
        {{8, 10, 0, 0}, {0,  0, 0, 0}},  // gpw
        {{8, 11, 1, 1}, {9, 12, 0, 1}},  // pwpw    -> completes T8, T9
        {{3, 13, 1, 1}, {0,  0, 0, 0}},  // pwdis   -> completes T3
    };
    const int doneCnt[10] = {2, 0, 0, 1, 2, 0, 2, 0, 2, 1};
    const int doneT[10][2] = {{0,1},{0,0},{0,0},{2,0},{4,5},{0,0},{6,7},{0,0},{8,9},{3,0}};

    // ---- one-time conversions & zeroing ----
    wconv_t<<<16, 256, 0, stream>>>(W_blocks, attn_W1, wtbf);
    hipMemsetAsync(statsraw, 0, (2560 + 2560 + 16) * sizeof(float), stream);

    // ---- batched partitioned CSR build ----
    BuildArgs BA;
    ScanArgs  SAD, SAS;
    ScatArgs  CA;
    SortArgs  SO;
    DegArgs   DA;
    for (int r = 0; r < 10; r++) {
        BA.esrc[r] = (const int*)d_in[relSrc[r]];
        BA.edst[r] = (const int*)d_in[relSrc[r] + 1];
        BA.E[r] = relE[r];
        CA.esrc[r] = BA.esrc[r]; CA.edst[r] = BA.edst[r]; CA.E[r] = relE[r];
        SO.cursorBase[r] = cursorBase[r];
        SO.nd[r] = relNd[r];
        DA.degsBase[r] = degsBase[r];
        DA.ns[r] = relNs[r];
    }
    for (int i = 0; i < 11; i++) {
        BA.cumBlk[i] = cumBlk[i]; BA.dstColBase[i] = dstColBase[i]; BA.srcColBase[i] = srcColBase[i];
        SAD.colBase[i] = dstColBase[i]; SAD.cumBlk[i] = cumBlk[i];
        SAS.colBase[i] = srcColBase[i]; SAS.cumBlk[i] = cumBlk[i];
        CA.cumBlk[i] = cumBlk[i]; CA.dstColBase[i] = dstColBase[i]; CA.srcColBase[i] = srcColBase[i];
        SO.dstColBase[i] = dstColBase[i];
        DA.colBase[i] = srcColBase[i];
    }
    BA.histD = histD; BA.histS = histS;
    SAD.hist = histD; SAD.totals = totalsD;
    SAS.hist = histS; SAS.totals = totalsS;
    CA.histD = histD; CA.colbaseD = colbaseD;
    CA.histS = histS; CA.colbaseS = colbaseS;
    CA.epart = epart; CA.spart = spart;
    SO.epart = epart; SO.colbase = colbaseD;
    SO.csrE = csrE; SO.rowStart = rowStart; SO.rowCnt = rowCnt;
    DA.spart = spart; DA.colbase = colbaseS; DA.degs = degs;

    part_count<<<556, 256, 0, stream>>>(BA);
    col_scan<<<2194, 256, 0, stream>>>(SAD);
    col_scan<<<2194, 256, 0, stream>>>(SAS);
    base_scan<<<1, 256, 0, stream>>>(totalsD, colbaseD, 2194);
    base_scan<<<1, 256, 0, stream>>>(totalsS, colbaseS, 2194);
    scatter_all<<<556, 256, 0, stream>>>(CA);
    bucket_sort<<<2194, 256, 0, stream>>>(SO);
    deg_count<<<2194, 256, 0, stream>>>(DA);

    // ---- per-rel scaled-xconv + gather + GEMM + L3-hot attention ----
    for (int r = 0; r < 10; r++) {
        xconv_scaled<<<(relNs[r] + 3) / 4, 256, 0, stream>>>(
            feats[relFeat[r]], degs + degsBase[r], xbf, relNs[r]);
        gather_bf16<<<relNd[r] / 4, 256, 0, stream>>>(
            xbf, rowStart + cursorBase[r], rowCnt + cursorBase[r],
            csrE, epart, colbaseD, dstColBase[r], aggb, relNd[r]);
        if (relNjob[r] == 2) {
            const GJob& G0 = relJob[r][0];
            const GJob& G1 = relJob[r][1];
            gemm_mfma2<<<relNd[r] / 64, 256, 0, stream>>>(
                (const unsigned short*)aggb,
                wtbf + (size_t)G0.widx * 16384, wtbf + (size_t)G1.widx * 16384,
                Vb[G0.tid], Vb[G1.tid], G0.accum, G1.accum, G0.stats, G1.stats,
                statsraw + (size_t)G0.tid * 256, statsraw + (size_t)G1.tid * 256);
        } else {
            const GJob& G = relJob[r][0];
            gemm_mfma<<<relNd[r] / 64, 256, 0, stream>>>(
                (const unsigned short*)aggb, wtbf + (size_t)G.widx * 16384,
                Vb[G.tid], G.accum, G.stats, statsraw + (size_t)G.tid * 256);
        }
        for (int k = 0; k < doneCnt[r]; k++) {
            int t = doneT[r][k];
            attn_t<<<Mt[t] / 64, 256, 0, stream>>>(
                Vb[t], statsraw + (size_t)t * 256, 1.0f / Mt[t],
                bn_gamma + blk[t] * 128, bn_beta + blk[t] * 128, prelu_a + blk[t],
                wtbf + (size_t)15 * 16384, attn_b1, attn_w2, Ssum + t);
        }
    }

    FinArgs fa;
    for (int t = 0; t < 10; t++) fa.Ms[t] = Mt[t];
    bn_finalize<<<10, 128, 0, stream>>>(statsraw, statsfin, fa);

    CombArgs CD;
    CD.stats = statsfin; CD.gam = bn_gamma; CD.bet = bn_beta; CD.pa = prelu_a; CD.S = Ssum;
    CD.cum[0] = 0;
    for (int p = 0; p < 5; p++) {
        CD.outp[p] = out + offT[p];
        CD.va[p] = Vb[p * 2];
        CD.vb[p] = Vb[p * 2 + 1];
        CD.ta[p] = p * 2; CD.tb[p] = p * 2 + 1;
        CD.blka[p] = blk[p * 2]; CD.blkb[p] = blk[p * 2 + 1];
        CD.invM[p] = 1.0f / Mt[p * 2];
        CD.cum[p + 1] = CD.cum[p] + Mt[p * 2] / 16;   // Mt*128/(256*8) blocks
    }
    combine_all<<<CD.cum[5], 256, 0, stream>>>(CD);
}